// Round 1
// baseline (1605.489 us; speedup 1.0000x reference)
//
#include <hip/hip_runtime.h>
#include <hip/hip_bf16.h>

// Decoder block: self-MHA -> add+LN -> cross-MHA -> add+LN(resid=orig x) -> FFN -> add+LN
// B=4 S=1024 H=1024 NH=16 d=64.  All linears: bf16 MFMA GEMM (fp32 in/out).
// Attention: fp32 flash-style (online softmax), logits = qk/64 + (1-mask)*(-1e10)/8.

typedef float float4v __attribute__((ext_vector_type(4)));
typedef __bf16 bf16x8 __attribute__((ext_vector_type(8)));
typedef unsigned short ushort8 __attribute__((ext_vector_type(8)));
typedef unsigned int uint4v __attribute__((ext_vector_type(4)));

__device__ inline unsigned short f2bf1(float f) {
    unsigned u = __builtin_bit_cast(unsigned, f);
    u += 0x7fffu + ((u >> 16) & 1u);
    return (unsigned short)(u >> 16);
}
__device__ inline unsigned f2bf2(float lo, float hi) {
    unsigned a = __builtin_bit_cast(unsigned, lo);
    a += 0x7fffu + ((a >> 16) & 1u);
    unsigned b = __builtin_bit_cast(unsigned, hi);
    b += 0x7fffu + ((b >> 16) & 1u);
    return (a >> 16) | (b & 0xffff0000u);
}

// ---------------- GEMM: C[M,N] = A[M,K] @ W[K,N] + bias, optional ReLU ----------
// 128x128 block tile, BK=32, 256 threads (4 waves, 2x2 of 64x64 wave tiles),
// mfma_f32_16x16x32_bf16, 4x4 tiles per wave.
template <int RELU>
__global__ __launch_bounds__(256) void gemm_kernel(
    const float* __restrict__ A, const float* __restrict__ W,
    const float* __restrict__ bias, float* __restrict__ C,
    int M, int N, int K)
{
    __shared__ __align__(16) unsigned short As[128][40];  // [m][k] pad 32->40
    __shared__ __align__(16) unsigned short Bs[128][40];  // [n][k] (W transposed)

    const int tid = threadIdx.x;
    const int m0 = blockIdx.y * 128, n0 = blockIdx.x * 128;
    const int w = tid >> 6, lane = tid & 63;
    const int wm = (w >> 1) * 64, wn = (w & 1) * 64;
    const int lr = lane & 15, quad = lane >> 4;

    float4v acc[4][4];
#pragma unroll
    for (int i = 0; i < 4; i++)
#pragma unroll
        for (int j = 0; j < 4; j++) acc[i][j] = 0.f;

    const int arow = tid >> 1, acol = (tid & 1) * 16;  // A: 128 rows x 32 k
    const int bk = tid & 31, bn = (tid >> 5) * 16;     // W: 32 k-rows x 128 n

    const float* Ap = A + (size_t)(m0 + arow) * K + acol;
    const float* Wp = W + (size_t)bk * N + (n0 + bn);

    for (int k0 = 0; k0 < K; k0 += 32) {
        float4v a0 = ((const float4v*)Ap)[0];
        float4v a1 = ((const float4v*)Ap)[1];
        float4v a2 = ((const float4v*)Ap)[2];
        float4v a3 = ((const float4v*)Ap)[3];
        float4v b0 = ((const float4v*)Wp)[0];
        float4v b1 = ((const float4v*)Wp)[1];
        float4v b2 = ((const float4v*)Wp)[2];
        float4v b3 = ((const float4v*)Wp)[3];

        uint4v pa0 = { f2bf2(a0.x, a0.y), f2bf2(a0.z, a0.w), f2bf2(a1.x, a1.y), f2bf2(a1.z, a1.w) };
        uint4v pa1 = { f2bf2(a2.x, a2.y), f2bf2(a2.z, a2.w), f2bf2(a3.x, a3.y), f2bf2(a3.z, a3.w) };
        *(uint4v*)&As[arow][acol]     = pa0;
        *(uint4v*)&As[arow][acol + 8] = pa1;

        Bs[bn + 0][bk] = f2bf1(b0.x);  Bs[bn + 1][bk] = f2bf1(b0.y);
        Bs[bn + 2][bk] = f2bf1(b0.z);  Bs[bn + 3][bk] = f2bf1(b0.w);
        Bs[bn + 4][bk] = f2bf1(b1.x);  Bs[bn + 5][bk] = f2bf1(b1.y);
        Bs[bn + 6][bk] = f2bf1(b1.z);  Bs[bn + 7][bk] = f2bf1(b1.w);
        Bs[bn + 8][bk] = f2bf1(b2.x);  Bs[bn + 9][bk] = f2bf1(b2.y);
        Bs[bn +10][bk] = f2bf1(b2.z);  Bs[bn +11][bk] = f2bf1(b2.w);
        Bs[bn +12][bk] = f2bf1(b3.x);  Bs[bn +13][bk] = f2bf1(b3.y);
        Bs[bn +14][bk] = f2bf1(b3.z);  Bs[bn +15][bk] = f2bf1(b3.w);
        __syncthreads();

        bf16x8 af[4], bf[4];
#pragma unroll
        for (int i = 0; i < 4; i++)
            af[i] = __builtin_bit_cast(bf16x8, *(const ushort8*)&As[wm + i * 16 + lr][quad * 8]);
#pragma unroll
        for (int j = 0; j < 4; j++)
            bf[j] = __builtin_bit_cast(bf16x8, *(const ushort8*)&Bs[wn + j * 16 + lr][quad * 8]);
#pragma unroll
        for (int i = 0; i < 4; i++)
#pragma unroll
            for (int j = 0; j < 4; j++)
                acc[i][j] = __builtin_amdgcn_mfma_f32_16x16x32_bf16(af[i], bf[j], acc[i][j], 0, 0, 0);
        __syncthreads();

        Ap += 32;
        Wp += (size_t)32 * N;
    }

#pragma unroll
    for (int j = 0; j < 4; j++) {
        int col = n0 + wn + j * 16 + lr;
        float bv = bias[col];
#pragma unroll
        for (int i = 0; i < 4; i++) {
#pragma unroll
            for (int r = 0; r < 4; r++) {
                int row = m0 + wm + i * 16 + quad * 4 + r;
                float v = acc[i][j][r] + bv;
                if (RELU) v = fmaxf(v, 0.f);
                C[(size_t)row * N + col] = v;
            }
        }
    }
}

// ---------------- Flash attention (fp32), one block per (b, h, 64 q-rows) -------
// logits = (q.k)/64 + (1-mask)*(-1e10)/8 ; out[b,s,h*64+d]
__global__ __launch_bounds__(256) void attn_kernel(
    const float* __restrict__ Q, const float* __restrict__ K,
    const float* __restrict__ V, const int* __restrict__ mask,
    float* __restrict__ O)
{
    __shared__ __align__(16) float Qs[64][68];
    __shared__ __align__(16) float Kt[64][68];   // Kt[d][key]
    __shared__ __align__(16) float Vs[64][68];   // Vs[key][d]
    __shared__ __align__(16) float Ps[64][68];   // scores / probs [q][key]
    __shared__ float mi[64], li[64], al[64], madd[64];

    const int tid = threadIdx.x;
    const int b = blockIdx.z, h = blockIdx.y, q0 = blockIdx.x * 64;
    const size_t base = ((size_t)b * 1024) * 1024 + (size_t)h * 64;

    {   // load Q tile (64 x 64)
        int r = tid >> 2, seg = tid & 3;
        const float4v* src = (const float4v*)(Q + base + (size_t)(q0 + r) * 1024 + seg * 16);
        float4v* dst = (float4v*)&Qs[r][seg * 16];
#pragma unroll
        for (int t = 0; t < 4; t++) dst[t] = src[t];
    }
    if (tid < 64) { mi[tid] = -1e30f; li[tid] = 0.f; }

    float o0[8] = {0,0,0,0,0,0,0,0}, o1[8] = {0,0,0,0,0,0,0,0};
    const int qp = tid >> 3;       // q rows {qp, qp+32}
    const int doct = tid & 7;      // d = doct*8 .. +8
    const int tq = tid >> 3, tk = tid & 7;

    for (int kb = 0; kb < 16; ++kb) {
        const int s0 = kb * 64;
        __syncthreads();   // previous iteration's reads of Kt/Vs/Ps done
        {
            int r = tid >> 2, seg = tid & 3;
            const float4v* ks = (const float4v*)(K + base + (size_t)(s0 + r) * 1024 + seg * 16);
#pragma unroll
            for (int t = 0; t < 4; t++) {
                float4v kv = ks[t];
                int d = seg * 16 + t * 4;
                Kt[d + 0][r] = kv.x; Kt[d + 1][r] = kv.y;
                Kt[d + 2][r] = kv.z; Kt[d + 3][r] = kv.w;
            }
            const float4v* vs = (const float4v*)(V + base + (size_t)(s0 + r) * 1024 + seg * 16);
            float4v* vd = (float4v*)&Vs[r][seg * 16];
#pragma unroll
            for (int t = 0; t < 4; t++) vd[t] = vs[t];
        }
        if (tid < 64)
            madd[tid] = (1.0f - (float)mask[b * 1024 + s0 + tid]) * (-1.25e9f);
        __syncthreads();

        {   // scores: thread -> 2 q rows x 8 keys
            float acc0[8] = {0,0,0,0,0,0,0,0}, acc1[8] = {0,0,0,0,0,0,0,0};
            for (int dd = 0; dd < 64; ++dd) {
                float qa = Qs[tq][dd], qb = Qs[tq + 32][dd];
                const float* kr = &Kt[dd][tk * 8];
#pragma unroll
                for (int j = 0; j < 8; j++) {
                    float kv = kr[j];
                    acc0[j] += qa * kv;
                    acc1[j] += qb * kv;
                }
            }
#pragma unroll
            for (int j = 0; j < 8; j++) {
                Ps[tq][tk * 8 + j]      = acc0[j] * 0.015625f + madd[tk * 8 + j];
                Ps[tq + 32][tk * 8 + j] = acc1[j] * 0.015625f + madd[tk * 8 + j];
            }
        }
        __syncthreads();

        if (tid < 64) {   // online softmax update, one thread per q row
            int r = tid;
            float rowm = -1e30f;
            for (int j = 0; j < 64; j++) rowm = fmaxf(rowm, Ps[r][j]);
            float mnew = fmaxf(mi[r], rowm);
            float s = 0.f;
            for (int j = 0; j < 64; j++) {
                float p = __expf(Ps[r][j] - mnew);
                Ps[r][j] = p;
                s += p;
            }
            float a = __expf(mi[r] - mnew);
            al[r] = a;
            li[r] = li[r] * a + s;
            mi[r] = mnew;
        }
        __syncthreads();

        {   // PV: thread -> 2 q rows x 8 d
            float a0 = al[qp], a1 = al[qp + 32];
#pragma unroll
            for (int i = 0; i < 8; i++) { o0[i] *= a0; o1[i] *= a1; }
            for (int j = 0; j < 64; ++j) {
                float pa = Ps[qp][j], pb = Ps[qp + 32][j];
                const float* vr = &Vs[j][doct * 8];
#pragma unroll
                for (int i = 0; i < 8; i++) {
                    float vv = vr[i];
                    o0[i] += pa * vv;
                    o1[i] += pb * vv;
                }
            }
        }
    }

    {
        float i0 = 1.0f / li[qp], i1 = 1.0f / li[qp + 32];
        float* d0 = O + base + (size_t)(q0 + qp) * 1024 + doct * 8;
        float* d1 = O + base + (size_t)(q0 + qp + 32) * 1024 + doct * 8;
#pragma unroll
        for (int i = 0; i < 8; i++) { d0[i] = o0[i] * i0; d1[i] = o1[i] * i1; }
    }
}

// ---------------- fused residual-add + LayerNorm (row = 1024) -------------------
__global__ __launch_bounds__(256) void add_ln_kernel(
    const float* __restrict__ X, const float* __restrict__ R,
    const float* __restrict__ g, const float* __restrict__ bb,
    float* __restrict__ out)
{
    const int row = blockIdx.x, tid = threadIdx.x;
    const float4v* x4 = (const float4v*)(X + (size_t)row * 1024);
    const float4v* r4 = (const float4v*)(R + (size_t)row * 1024);
    float4v z = x4[tid] + r4[tid];
    float s = z.x + z.y + z.z + z.w;
    float sq = z.x * z.x + z.y * z.y + z.z * z.z + z.w * z.w;
#pragma unroll
    for (int off = 32; off > 0; off >>= 1) {
        s += __shfl_down(s, off);
        sq += __shfl_down(sq, off);
    }
    __shared__ float ws[4], wsq[4];
    __shared__ float sm, sr;
    if ((tid & 63) == 0) { ws[tid >> 6] = s; wsq[tid >> 6] = sq; }
    __syncthreads();
    if (tid == 0) {
        float S1 = ws[0] + ws[1] + ws[2] + ws[3];
        float S2 = wsq[0] + wsq[1] + wsq[2] + wsq[3];
        float mean = S1 * (1.0f / 1024.0f);
        float var = S2 * (1.0f / 1024.0f) - mean * mean;
        sm = mean;
        sr = rsqrtf(var + 1e-5f);
    }
    __syncthreads();
    float mean = sm, rstd = sr;
    const float4v* g4 = (const float4v*)g;
    const float4v* b4 = (const float4v*)bb;
    float4v res = g4[tid] * ((z - mean) * rstd) + b4[tid];
    ((float4v*)(out + (size_t)row * 1024))[tid] = res;
}

// --------------------------------------------------------------------------------
extern "C" void kernel_launch(void* const* d_in, const int* in_sizes, int n_in,
                              void* d_out, int out_size, void* d_ws, size_t ws_size,
                              hipStream_t stream)
{
    const float* x     = (const float*)d_in[0];
    const int*   smask = (const int*)d_in[1];
    const float* cx    = (const float*)d_in[2];
    const int*   cmask = (const int*)d_in[3];
    // d_in[4] = num_head (16), unused
    const float* sWq = (const float*)d_in[5],  *sbq = (const float*)d_in[6];
    const float* sWk = (const float*)d_in[7],  *sbk = (const float*)d_in[8];
    const float* sWv = (const float*)d_in[9],  *sbv = (const float*)d_in[10];
    const float* sWo = (const float*)d_in[11], *sbo = (const float*)d_in[12];
    const float* cWq = (const float*)d_in[13], *cbq = (const float*)d_in[14];
    const float* cWk = (const float*)d_in[15], *cbk = (const float*)d_in[16];
    const float* cWv = (const float*)d_in[17], *cbv = (const float*)d_in[18];
    const float* cWo = (const float*)d_in[19], *cbo = (const float*)d_in[20];
    const float* g   = (const float*)d_in[21], *bb  = (const float*)d_in[22];
    const float* W1  = (const float*)d_in[23], *b1  = (const float*)d_in[24];
    const float* W2  = (const float*)d_in[25], *b2  = (const float*)d_in[26];
    float* out = (float*)d_out;

    const size_t SZ = (size_t)4096 * 1024;  // 4M floats
    float* A   = (float*)d_ws;     // q / generic
    float* Bk  = A + SZ;           // k
    float* Cv  = Bk + SZ;          // v
    float* T   = Cv + SZ;          // attention out
    float* SAN = T + SZ;           // LN(self-att + x)
    float* HH  = SAN + SZ;         // LN(cross-att + x)
    float* MID = HH + SZ;          // FFN intermediate, 16M floats
    // total: 40M floats = 160 MB of d_ws

    dim3 blk(256);
    dim3 gP(1024 / 128, 4096 / 128);     // N=1024 GEMMs
    dim3 gF1(4096 / 128, 4096 / 128);    // FFN1 N=4096
    dim3 gA(16, 16, 4);                  // attention: (q-tiles, heads, batch)

    // ---- self attention ----
    gemm_kernel<0><<<gP, blk, 0, stream>>>(x, sWq, sbq, A, 4096, 1024, 1024);
    gemm_kernel<0><<<gP, blk, 0, stream>>>(x, sWk, sbk, Bk, 4096, 1024, 1024);
    gemm_kernel<0><<<gP, blk, 0, stream>>>(x, sWv, sbv, Cv, 4096, 1024, 1024);
    attn_kernel<<<gA, blk, 0, stream>>>(A, Bk, Cv, smask, T);
    gemm_kernel<0><<<gP, blk, 0, stream>>>(T, sWo, sbo, A, 4096, 1024, 1024);
    add_ln_kernel<<<4096, blk, 0, stream>>>(A, x, g, bb, SAN);

    // ---- cross attention (residual uses ORIGINAL x per reference) ----
    gemm_kernel<0><<<gP, blk, 0, stream>>>(SAN, cWq, cbq, A, 4096, 1024, 1024);
    gemm_kernel<0><<<gP, blk, 0, stream>>>(cx, cWk, cbk, Bk, 4096, 1024, 1024);
    gemm_kernel<0><<<gP, blk, 0, stream>>>(cx, cWv, cbv, Cv, 4096, 1024, 1024);
    attn_kernel<<<gA, blk, 0, stream>>>(A, Bk, Cv, cmask, T);
    gemm_kernel<0><<<gP, blk, 0, stream>>>(T, cWo, cbo, A, 4096, 1024, 1024);
    add_ln_kernel<<<4096, blk, 0, stream>>>(A, x, g, bb, HH);

    // ---- FFN ----
    gemm_kernel<1><<<gF1, blk, 0, stream>>>(HH, W1, b1, MID, 4096, 4096, 1024);
    gemm_kernel<0><<<gP, blk, 0, stream>>>(MID, W2, b2, A, 4096, 1024, 4096);
    add_ln_kernel<<<4096, blk, 0, stream>>>(A, HH, g, bb, out);
}

// Round 2
// 1174.612 us; speedup vs baseline: 1.3668x; 1.3668x over previous
//
#include <hip/hip_runtime.h>
#include <hip/hip_bf16.h>

// Decoder block: self-MHA -> add+LN -> cross-MHA -> add+LN(resid=orig x) -> FFN -> add+LN
// B=4 S=1024 H=1024 NH=16 d=64.  Linears: bf16 MFMA GEMM (fp32 in/out).
// Attention: bf16 MFMA flash attention, register-resident online softmax.
// logits = qk/64 + (1-mask)*(-1e10)/8  (double-scale per reference).

typedef float float4v __attribute__((ext_vector_type(4)));
typedef __bf16 bf16x8 __attribute__((ext_vector_type(8)));
typedef unsigned short ushort8 __attribute__((ext_vector_type(8)));
typedef unsigned int uint4v __attribute__((ext_vector_type(4)));

__device__ inline unsigned short f2bf1(float f) {
    unsigned u = __builtin_bit_cast(unsigned, f);
    u += 0x7fffu + ((u >> 16) & 1u);
    return (unsigned short)(u >> 16);
}
__device__ inline unsigned f2bf2(float lo, float hi) {
    unsigned a = __builtin_bit_cast(unsigned, lo);
    a += 0x7fffu + ((a >> 16) & 1u);
    unsigned b = __builtin_bit_cast(unsigned, hi);
    b += 0x7fffu + ((b >> 16) & 1u);
    return (a >> 16) | (b & 0xffff0000u);
}

// ---------------- GEMM: C[M,N] = A[M,K] @ W[K,N] + bias, optional ReLU ----------
// 128x128 block tile, BK=32, 256 threads (4 waves, 2x2 of 64x64 wave tiles),
// mfma_f32_16x16x32_bf16, 4x4 tiles per wave.  (unchanged from round 1)
template <int RELU>
__global__ __launch_bounds__(256) void gemm_kernel(
    const float* __restrict__ A, const float* __restrict__ W,
    const float* __restrict__ bias, float* __restrict__ C,
    int M, int N, int K)
{
    __shared__ __align__(16) unsigned short As[128][40];  // [m][k] pad 32->40
    __shared__ __align__(16) unsigned short Bs[128][40];  // [n][k] (W transposed)

    const int tid = threadIdx.x;
    const int m0 = blockIdx.y * 128, n0 = blockIdx.x * 128;
    const int w = tid >> 6, lane = tid & 63;
    const int wm = (w >> 1) * 64, wn = (w & 1) * 64;
    const int lr = lane & 15, quad = lane >> 4;

    float4v acc[4][4];
#pragma unroll
    for (int i = 0; i < 4; i++)
#pragma unroll
        for (int j = 0; j < 4; j++) acc[i][j] = 0.f;

    const int arow = tid >> 1, acol = (tid & 1) * 16;  // A: 128 rows x 32 k
    const int bk = tid & 31, bn = (tid >> 5) * 16;     // W: 32 k-rows x 128 n

    const float* Ap = A + (size_t)(m0 + arow) * K + acol;
    const float* Wp = W + (size_t)bk * N + (n0 + bn);

    for (int k0 = 0; k0 < K; k0 += 32) {
        float4v a0 = ((const float4v*)Ap)[0];
        float4v a1 = ((const float4v*)Ap)[1];
        float4v a2 = ((const float4v*)Ap)[2];
        float4v a3 = ((const float4v*)Ap)[3];
        float4v b0 = ((const float4v*)Wp)[0];
        float4v b1 = ((const float4v*)Wp)[1];
        float4v b2 = ((const float4v*)Wp)[2];
        float4v b3 = ((const float4v*)Wp)[3];

        uint4v pa0 = { f2bf2(a0.x, a0.y), f2bf2(a0.z, a0.w), f2bf2(a1.x, a1.y), f2bf2(a1.z, a1.w) };
        uint4v pa1 = { f2bf2(a2.x, a2.y), f2bf2(a2.z, a2.w), f2bf2(a3.x, a3.y), f2bf2(a3.z, a3.w) };
        *(uint4v*)&As[arow][acol]     = pa0;
        *(uint4v*)&As[arow][acol + 8] = pa1;

        Bs[bn + 0][bk] = f2bf1(b0.x);  Bs[bn + 1][bk] = f2bf1(b0.y);
        Bs[bn + 2][bk] = f2bf1(b0.z);  Bs[bn + 3][bk] = f2bf1(b0.w);
        Bs[bn + 4][bk] = f2bf1(b1.x);  Bs[bn + 5][bk] = f2bf1(b1.y);
        Bs[bn + 6][bk] = f2bf1(b1.z);  Bs[bn + 7][bk] = f2bf1(b1.w);
        Bs[bn + 8][bk] = f2bf1(b2.x);  Bs[bn + 9][bk] = f2bf1(b2.y);
        Bs[bn +10][bk] = f2bf1(b2.z);  Bs[bn +11][bk] = f2bf1(b2.w);
        Bs[bn +12][bk] = f2bf1(b3.x);  Bs[bn +13][bk] = f2bf1(b3.y);
        Bs[bn +14][bk] = f2bf1(b3.z);  Bs[bn +15][bk] = f2bf1(b3.w);
        __syncthreads();

        bf16x8 af[4], bf[4];
#pragma unroll
        for (int i = 0; i < 4; i++)
            af[i] = __builtin_bit_cast(bf16x8, *(const ushort8*)&As[wm + i * 16 + lr][quad * 8]);
#pragma unroll
        for (int j = 0; j < 4; j++)
            bf[j] = __builtin_bit_cast(bf16x8, *(const ushort8*)&Bs[wn + j * 16 + lr][quad * 8]);
#pragma unroll
        for (int i = 0; i < 4; i++)
#pragma unroll
            for (int j = 0; j < 4; j++)
                acc[i][j] = __builtin_amdgcn_mfma_f32_16x16x32_bf16(af[i], bf[j], acc[i][j], 0, 0, 0);
        __syncthreads();

        Ap += 32;
        Wp += (size_t)32 * N;
    }

#pragma unroll
    for (int j = 0; j < 4; j++) {
        int col = n0 + wn + j * 16 + lr;
        float bv = bias[col];
#pragma unroll
        for (int i = 0; i < 4; i++) {
#pragma unroll
            for (int r = 0; r < 4; r++) {
                int row = m0 + wm + i * 16 + quad * 4 + r;
                float v = acc[i][j][r] + bv;
                if (RELU) v = fmaxf(v, 0.f);
                C[(size_t)row * N + col] = v;
            }
        }
    }
}

// ---------------- MFMA flash attention -----------------------------------------
// One block per (b, h, 128 q-rows). 4 waves, each owns 32 q-rows (2 row-tiles).
// K-tile = 64 keys. Online softmax fully in registers: C-layout row = quad*4+rr
// lives in the 16 lanes of a quad-group -> shfl_xor(1,2,4,8) row reduction.
// P round-trips LDS only for the C-layout -> A-layout transform.
__global__ __launch_bounds__(256) void attn_mfma(
    const float* __restrict__ Q, const float* __restrict__ K,
    const float* __restrict__ V, const int* __restrict__ mask,
    float* __restrict__ O)
{
    __shared__ __align__(16) unsigned short Ks[64][72];   // [key][d]
    __shared__ __align__(16) unsigned short Vt[64][72];   // [d][key] (transposed)
    __shared__ __align__(16) unsigned short Pb[128][72];  // [q-row][key] bf16 probs
    __shared__ float madd[64];

    const int tid = threadIdx.x;
    const int b = blockIdx.z, h = blockIdx.y, q0 = blockIdx.x * 128;
    const int w = tid >> 6, lane = tid & 63;
    const int lr = lane & 15, quad = lane >> 4;
    const int wm = w * 32;

    const float4v zf = {0.f, 0.f, 0.f, 0.f};

    // Q fragments (A layout: m=lr, k=quad*8+j), scaled by 1/64, held in regs.
    bf16x8 qf[2][2];
#pragma unroll
    for (int i = 0; i < 2; i++)
#pragma unroll
        for (int c = 0; c < 2; c++) {
            const float* qp = Q + ((size_t)(b * 1024 + q0 + wm + i * 16 + lr)) * 1024
                              + h * 64 + c * 32 + quad * 8;
            float4v a = ((const float4v*)qp)[0] * 0.015625f;
            float4v bq = ((const float4v*)qp)[1] * 0.015625f;
            uint4v u = { f2bf2(a.x, a.y), f2bf2(a.z, a.w), f2bf2(bq.x, bq.y), f2bf2(bq.z, bq.w) };
            qf[i][c] = __builtin_bit_cast(bf16x8, u);
        }

    float4v oac[2][4];
    float m_reg[2][4], l_reg[2][4];
#pragma unroll
    for (int i = 0; i < 2; i++) {
#pragma unroll
        for (int j = 0; j < 4; j++) oac[i][j] = zf;
#pragma unroll
        for (int rr = 0; rr < 4; rr++) { m_reg[i][rr] = -3e38f; l_reg[i][rr] = 0.f; }
    }

    const int kr = tid >> 2, seg = tid & 3;  // staging: 4 threads per key row

    for (int kb = 0; kb < 16; ++kb) {
        const int s0 = kb * 64;
        __syncthreads();   // prev iter's QK reads of Ks and PV reads of Vt done
        {
            const float* kp = K + ((size_t)(b * 1024 + s0 + kr)) * 1024 + h * 64 + seg * 16;
            float4v k0 = ((const float4v*)kp)[0];
            float4v k1 = ((const float4v*)kp)[1];
            float4v k2 = ((const float4v*)kp)[2];
            float4v k3 = ((const float4v*)kp)[3];
            uint4v u0 = { f2bf2(k0.x, k0.y), f2bf2(k0.z, k0.w), f2bf2(k1.x, k1.y), f2bf2(k1.z, k1.w) };
            uint4v u1 = { f2bf2(k2.x, k2.y), f2bf2(k2.z, k2.w), f2bf2(k3.x, k3.y), f2bf2(k3.z, k3.w) };
            *(uint4v*)&Ks[kr][seg * 16]     = u0;
            *(uint4v*)&Ks[kr][seg * 16 + 8] = u1;

            const float* vp = V + ((size_t)(b * 1024 + s0 + kr)) * 1024 + h * 64 + seg * 16;
            float4v v4[4];
            v4[0] = ((const float4v*)vp)[0];
            v4[1] = ((const float4v*)vp)[1];
            v4[2] = ((const float4v*)vp)[2];
            v4[3] = ((const float4v*)vp)[3];
            const float* vs = (const float*)v4;
#pragma unroll
            for (int t = 0; t < 16; t++)
                Vt[seg * 16 + t][kr] = f2bf1(vs[t]);
        }
        if (tid < 64)
            madd[tid] = (1.0f - (float)mask[b * 1024 + s0 + tid]) * (-1.25e9f);
        __syncthreads();

        // ---- QK^T: logits for 32 q-rows x 64 keys per wave ----
        float4v sa[2][4];
#pragma unroll
        for (int j = 0; j < 4; j++) {
            bf16x8 kf0 = __builtin_bit_cast(bf16x8, *(const ushort8*)&Ks[j * 16 + lr][quad * 8]);
            bf16x8 kf1 = __builtin_bit_cast(bf16x8, *(const ushort8*)&Ks[j * 16 + lr][32 + quad * 8]);
            sa[0][j] = __builtin_amdgcn_mfma_f32_16x16x32_bf16(qf[0][0], kf0, zf, 0, 0, 0);
            sa[0][j] = __builtin_amdgcn_mfma_f32_16x16x32_bf16(qf[0][1], kf1, sa[0][j], 0, 0, 0);
            sa[1][j] = __builtin_amdgcn_mfma_f32_16x16x32_bf16(qf[1][0], kf0, zf, 0, 0, 0);
            sa[1][j] = __builtin_amdgcn_mfma_f32_16x16x32_bf16(qf[1][1], kf1, sa[1][j], 0, 0, 0);
        }
#pragma unroll
        for (int j = 0; j < 4; j++) {
            float ma = madd[j * 16 + lr];
            sa[0][j] += ma;
            sa[1][j] += ma;
        }

        // ---- online softmax, fully in registers ----
#pragma unroll
        for (int i = 0; i < 2; i++) {
#pragma unroll
            for (int rr = 0; rr < 4; rr++) {
                float rm = fmaxf(fmaxf(sa[i][0][rr], sa[i][1][rr]),
                                 fmaxf(sa[i][2][rr], sa[i][3][rr]));
                rm = fmaxf(rm, __shfl_xor(rm, 1));
                rm = fmaxf(rm, __shfl_xor(rm, 2));
                rm = fmaxf(rm, __shfl_xor(rm, 4));
                rm = fmaxf(rm, __shfl_xor(rm, 8));
                float mnew = fmaxf(m_reg[i][rr], rm);
                float al = __expf(m_reg[i][rr] - mnew);
                float p0 = __expf(sa[i][0][rr] - mnew);
                float p1 = __expf(sa[i][1][rr] - mnew);
                float p2 = __expf(sa[i][2][rr] - mnew);
                float p3 = __expf(sa[i][3][rr] - mnew);
                float rs = p0 + p1 + p2 + p3;
                rs += __shfl_xor(rs, 1);
                rs += __shfl_xor(rs, 2);
                rs += __shfl_xor(rs, 4);
                rs += __shfl_xor(rs, 8);
                l_reg[i][rr] = l_reg[i][rr] * al + rs;
                m_reg[i][rr] = mnew;
                const int row = wm + i * 16 + quad * 4 + rr;
                Pb[row][ 0 + lr] = f2bf1(p0);
                Pb[row][16 + lr] = f2bf1(p1);
                Pb[row][32 + lr] = f2bf1(p2);
                Pb[row][48 + lr] = f2bf1(p3);
                oac[i][0][rr] *= al;
                oac[i][1][rr] *= al;
                oac[i][2][rr] *= al;
                oac[i][3][rr] *= al;
            }
        }
        // Pb rows [wm, wm+32) written & read by the SAME wave -> no barrier needed.

        // ---- PV: O += P @ V ----
        bf16x8 pf[2][2];
#pragma unroll
        for (int i = 0; i < 2; i++)
#pragma unroll
            for (int c = 0; c < 2; c++)
                pf[i][c] = __builtin_bit_cast(bf16x8,
                    *(const ushort8*)&Pb[wm + i * 16 + lr][c * 32 + quad * 8]);
#pragma unroll
        for (int j = 0; j < 4; j++) {
            bf16x8 vf0 = __builtin_bit_cast(bf16x8, *(const ushort8*)&Vt[j * 16 + lr][quad * 8]);
            bf16x8 vf1 = __builtin_bit_cast(bf16x8, *(const ushort8*)&Vt[j * 16 + lr][32 + quad * 8]);
            oac[0][j] = __builtin_amdgcn_mfma_f32_16x16x32_bf16(pf[0][0], vf0, oac[0][j], 0, 0, 0);
            oac[0][j] = __builtin_amdgcn_mfma_f32_16x16x32_bf16(pf[0][1], vf1, oac[0][j], 0, 0, 0);
            oac[1][j] = __builtin_amdgcn_mfma_f32_16x16x32_bf16(pf[1][0], vf0, oac[1][j], 0, 0, 0);
            oac[1][j] = __builtin_amdgcn_mfma_f32_16x16x32_bf16(pf[1][1], vf1, oac[1][j], 0, 0, 0);
        }
    }

    // ---- epilogue: O / l, write out ----
#pragma unroll
    for (int i = 0; i < 2; i++)
#pragma unroll
        for (int rr = 0; rr < 4; rr++) {
            float inv = 1.0f / l_reg[i][rr];
            const int row = q0 + wm + i * 16 + quad * 4 + rr;
            float* op = O + ((size_t)(b * 1024 + row)) * 1024 + h * 64;
#pragma unroll
            for (int j = 0; j < 4; j++)
                op[j * 16 + lr] = oac[i][j][rr] * inv;
        }
}

// ---------------- fused residual-add + LayerNorm (row = 1024) -------------------
__global__ __launch_bounds__(256) void add_ln_kernel(
    const float* __restrict__ X, const float* __restrict__ R,
    const float* __restrict__ g, const float* __restrict__ bb,
    float* __restrict__ out)
{
    const int row = blockIdx.x, tid = threadIdx.x;
    const float4v* x4 = (const float4v*)(X + (size_t)row * 1024);
    const float4v* r4 = (const float4v*)(R + (size_t)row * 1024);
    float4v z = x4[tid] + r4[tid];
    float s = z.x + z.y + z.z + z.w;
    float sq = z.x * z.x + z.y * z.y + z.z * z.z + z.w * z.w;
#pragma unroll
    for (int off = 32; off > 0; off >>= 1) {
        s += __shfl_down(s, off);
        sq += __shfl_down(sq, off);
    }
    __shared__ float ws[4], wsq[4];
    __shared__ float sm, sr;
    if ((tid & 63) == 0) { ws[tid >> 6] = s; wsq[tid >> 6] = sq; }
    __syncthreads();
    if (tid == 0) {
        float S1 = ws[0] + ws[1] + ws[2] + ws[3];
        float S2 = wsq[0] + wsq[1] + wsq[2] + wsq[3];
        float mean = S1 * (1.0f / 1024.0f);
        float var = S2 * (1.0f / 1024.0f) - mean * mean;
        sm = mean;
        sr = rsqrtf(var + 1e-5f);
    }
    __syncthreads();
    float mean = sm, rstd = sr;
    const float4v* g4 = (const float4v*)g;
    const float4v* b4 = (const float4v*)bb;
    float4v res = g4[tid] * ((z - mean) * rstd) + b4[tid];
    ((float4v*)(out + (size_t)row * 1024))[tid] = res;
}

// --------------------------------------------------------------------------------
extern "C" void kernel_launch(void* const* d_in, const int* in_sizes, int n_in,
                              void* d_out, int out_size, void* d_ws, size_t ws_size,
                              hipStream_t stream)
{
    const float* x     = (const float*)d_in[0];
    const int*   smask = (const int*)d_in[1];
    const float* cx    = (const float*)d_in[2];
    const int*   cmask = (const int*)d_in[3];
    // d_in[4] = num_head (16), unused
    const float* sWq = (const float*)d_in[5],  *sbq = (const float*)d_in[6];
    const float* sWk = (const float*)d_in[7],  *sbk = (const float*)d_in[8];
    const float* sWv = (const float*)d_in[9],  *sbv = (const float*)d_in[10];
    const float* sWo = (const float*)d_in[11], *sbo = (const float*)d_in[12];
    const float* cWq = (const float*)d_in[13], *cbq = (const float*)d_in[14];
    const float* cWk = (const float*)d_in[15], *cbk = (const float*)d_in[16];
    const float* cWv = (const float*)d_in[17], *cbv = (const float*)d_in[18];
    const float* cWo = (const float*)d_in[19], *cbo = (const float*)d_in[20];
    const float* g   = (const float*)d_in[21], *bb  = (const float*)d_in[22];
    const float* W1  = (const float*)d_in[23], *b1  = (const float*)d_in[24];
    const float* W2  = (const float*)d_in[25], *b2  = (const float*)d_in[26];
    float* out = (float*)d_out;

    const size_t SZ = (size_t)4096 * 1024;  // 4M floats
    float* A   = (float*)d_ws;     // q / generic
    float* Bk  = A + SZ;           // k
    float* Cv  = Bk + SZ;          // v
    float* T   = Cv + SZ;          // attention out
    float* SAN = T + SZ;           // LN(self-att + x)
    float* HH  = SAN + SZ;         // LN(cross-att + x)
    float* MID = HH + SZ;          // FFN intermediate, 16M floats
    // total: 40M floats = 160 MB of d_ws

    dim3 blk(256);
    dim3 gP(1024 / 128, 4096 / 128);     // N=1024 GEMMs
    dim3 gF1(4096 / 128, 4096 / 128);    // FFN1 N=4096
    dim3 gA(8, 16, 4);                   // attention: (q-tiles of 128, heads, batch)

    // ---- self attention ----
    gemm_kernel<0><<<gP, blk, 0, stream>>>(x, sWq, sbq, A, 4096, 1024, 1024);
    gemm_kernel<0><<<gP, blk, 0, stream>>>(x, sWk, sbk, Bk, 4096, 1024, 1024);
    gemm_kernel<0><<<gP, blk, 0, stream>>>(x, sWv, sbv, Cv, 4096, 1024, 1024);
    attn_mfma<<<gA, blk, 0, stream>>>(A, Bk, Cv, smask, T);
    gemm_kernel<0><<<gP, blk, 0, stream>>>(T, sWo, sbo, A, 4096, 1024, 1024);
    add_ln_kernel<<<4096, blk, 0, stream>>>(A, x, g, bb, SAN);

    // ---- cross attention (residual uses ORIGINAL x per reference) ----
    gemm_kernel<0><<<gP, blk, 0, stream>>>(SAN, cWq, cbq, A, 4096, 1024, 1024);
    gemm_kernel<0><<<gP, blk, 0, stream>>>(cx, cWk, cbk, Bk, 4096, 1024, 1024);
    gemm_kernel<0><<<gP, blk, 0, stream>>>(cx, cWv, cbv, Cv, 4096, 1024, 1024);
    attn_mfma<<<gA, blk, 0, stream>>>(A, Bk, Cv, cmask, T);
    gemm_kernel<0><<<gP, blk, 0, stream>>>(T, cWo, cbo, A, 4096, 1024, 1024);
    add_ln_kernel<<<4096, blk, 0, stream>>>(A, x, g, bb, HH);

    // ---- FFN ----
    gemm_kernel<1><<<gF1, blk, 0, stream>>>(HH, W1, b1, MID, 4096, 4096, 1024);
    gemm_kernel<0><<<gP, blk, 0, stream>>>(MID, W2, b2, A, 4096, 1024, 4096);
    add_ln_kernel<<<4096, blk, 0, stream>>>(A, HH, g, bb, out);
}

// Round 3
// 598.635 us; speedup vs baseline: 2.6819x; 1.9621x over previous
//
#include <hip/hip_runtime.h>
#include <hip/hip_bf16.h>

// Decoder block: self-MHA -> add+LN -> cross-MHA -> add+LN(resid=orig x) -> FFN -> add+LN
// B=4 S=1024 H=1024 NH=16 d=64.
// Strategy: pre-convert activations + pre-transpose weights to bf16 once per call,
// then m97-class bf16 GEMMs (global_load_lds width=16, XOR-swizzled LDS, BK=64).
// Attention: bf16 MFMA flash attention, register online softmax.
// logits = qk/64 + (1-mask)*(-1e10)/8 (double-scale per reference).

typedef float float4v __attribute__((ext_vector_type(4)));
typedef __bf16 bf16x8 __attribute__((ext_vector_type(8)));
typedef unsigned short ushort8 __attribute__((ext_vector_type(8)));
typedef unsigned int uint2v __attribute__((ext_vector_type(2)));

__device__ __forceinline__ unsigned short f2bf1(float f) {
    unsigned u = __builtin_bit_cast(unsigned, f);
    u += 0x7fffu + ((u >> 16) & 1u);
    return (unsigned short)(u >> 16);
}
__device__ __forceinline__ unsigned f2bf2(float lo, float hi) {
    unsigned a = __builtin_bit_cast(unsigned, lo);
    a += 0x7fffu + ((a >> 16) & 1u);
    unsigned b = __builtin_bit_cast(unsigned, hi);
    b += 0x7fffu + ((b >> 16) & 1u);
    return (a >> 16) | (b & 0xffff0000u);
}
__device__ __forceinline__ bf16x8 ldsv8(const unsigned short* p) {
    return __builtin_bit_cast(bf16x8, *(const ushort8*)p);
}
// async global->LDS, 16B per lane; LDS dest = wave-uniform base + lane*16
__device__ __forceinline__ void async16(const unsigned short* g, unsigned short* l) {
    __builtin_amdgcn_global_load_lds(
        (const __attribute__((address_space(1))) unsigned int*)(g),
        (__attribute__((address_space(3))) unsigned int*)(l),
        16, 0, 0);
}

// ---------------- GEMM: C[M,N] = A[M,K] @ Wt[N,K]^T + bias ---------------------
// A, Wt in bf16. 128x128 tile, BK=64, 4 waves 2x2 of 64x64, 16x16x32 MFMA.
// LDS layout: As[row][64k] contiguous (128B rows), 16B chunk c stored at c^(row&7)
// -> global_load_lds lane fetches chunk (lane&7)^(lane>>3&7); fragment ds_read_b128
// spreads all 32 banks at 2-way (free).
template <int RELU, int OUT_BF16>
__global__ __launch_bounds__(256) void gemm_bt(
    const unsigned short* __restrict__ A, const unsigned short* __restrict__ Bt,
    const float* __restrict__ bias, void* __restrict__ Cout,
    int M, int N, int K)
{
    __shared__ __align__(16) unsigned short As[128 * 64];
    __shared__ __align__(16) unsigned short Bs[128 * 64];

    const int tid = threadIdx.x;
    const int m0 = blockIdx.y * 128, n0 = blockIdx.x * 128;
    const int w = tid >> 6, lane = tid & 63;
    const int lr = lane & 15, quad = lane >> 4;
    const int wm = (w >> 1) * 64, wn = (w & 1) * 64;

    // staging: each wave stages 32 A-rows + 32 B-rows per K-iter (4+4 instrs)
    const int sr = lane >> 3, sc = lane & 7;
    const int fch = sc ^ sr;                       // swizzled source chunk
    const unsigned short* Ag = A + (size_t)(m0 + w * 32 + sr) * K + fch * 8;
    const unsigned short* Bg = Bt + (size_t)(n0 + w * 32 + sr) * K + fch * 8;
    unsigned short* Al = &As[(w * 32) * 64];
    unsigned short* Bl = &Bs[(w * 32) * 64];

    float4v acc[4][4];
#pragma unroll
    for (int i = 0; i < 4; i++)
#pragma unroll
        for (int j = 0; j < 4; j++) acc[i][j] = 0.f;

    const int ch0 = quad ^ (lr & 7);        // kk=0 chunk position
    const int ch1 = (4 + quad) ^ (lr & 7);  // kk=1 chunk position

    for (int k0 = 0; k0 < K; k0 += 64) {
#pragma unroll
        for (int i = 0; i < 4; i++) {
            async16(Ag + (size_t)(i * 8) * K + k0, Al + (i * 8) * 64);
            async16(Bg + (size_t)(i * 8) * K + k0, Bl + (i * 8) * 64);
        }
        __syncthreads();   // drains vmcnt -> staged data visible

#pragma unroll
        for (int kk = 0; kk < 2; kk++) {
            const int ch = kk ? ch1 : ch0;
            bf16x8 af[4], bf[4];
#pragma unroll
            for (int i = 0; i < 4; i++) {
                af[i] = ldsv8(&As[(wm + i * 16 + lr) * 64 + ch * 8]);
                bf[i] = ldsv8(&Bs[(wn + i * 16 + lr) * 64 + ch * 8]);
            }
#pragma unroll
            for (int i = 0; i < 4; i++)
#pragma unroll
                for (int j = 0; j < 4; j++)
                    acc[i][j] = __builtin_amdgcn_mfma_f32_16x16x32_bf16(af[i], bf[j], acc[i][j], 0, 0, 0);
        }
        __syncthreads();   // LDS reads done before next staging overwrites
    }

#pragma unroll
    for (int j = 0; j < 4; j++) {
        const int col = n0 + wn + j * 16 + lr;
        const float bv = bias[col];
#pragma unroll
        for (int i = 0; i < 4; i++) {
            const int row0 = m0 + wm + i * 16 + quad * 4;
#pragma unroll
            for (int r = 0; r < 4; r++) {
                float v = acc[i][j][r] + bv;
                if (RELU) v = fmaxf(v, 0.f);
                if (OUT_BF16)
                    ((unsigned short*)Cout)[(size_t)(row0 + r) * N + col] = f2bf1(v);
                else
                    ((float*)Cout)[(size_t)(row0 + r) * N + col] = v;
            }
        }
    }
}

// ---------------- MFMA flash attention (bf16 in/out) ----------------------------
// One block per (b, h, 128 q-rows); 4 waves x 32 q-rows. K staged via swizzled
// global_load_lds; V transposed manually; online softmax in registers.
__global__ __launch_bounds__(256) void attn_mfma(
    const unsigned short* __restrict__ Q, int qs,
    const unsigned short* __restrict__ K, const unsigned short* __restrict__ V, int kvs,
    const int* __restrict__ mask, unsigned short* __restrict__ O)
{
    __shared__ __align__(16) unsigned short Ks[64 * 64];   // [key][d], swizzled chunks
    __shared__ __align__(16) unsigned short Vt[64][72];    // [d][key]
    __shared__ __align__(16) unsigned short Pb[128][72];   // [q][key] bf16 probs
    __shared__ float madd[64];

    const int tid = threadIdx.x;
    const int b = blockIdx.z, h = blockIdx.y, q0 = blockIdx.x * 128;
    const int w = tid >> 6, lane = tid & 63;
    const int lr = lane & 15, quad = lane >> 4;
    const int wm = w * 32;
    const float4v zf = {0.f, 0.f, 0.f, 0.f};

    // Q fragments in registers (A-layout), raw bf16 bits; 1/64 applied post-MFMA
    bf16x8 qf[2][2];
#pragma unroll
    for (int i = 0; i < 2; i++)
#pragma unroll
        for (int c = 0; c < 2; c++)
            qf[i][c] = ldsv8(Q + (size_t)(b * 1024 + q0 + wm + i * 16 + lr) * qs
                             + h * 64 + c * 32 + quad * 8);

    const int sr = lane >> 3, sc = lane & 7;
    const int fch = sc ^ sr;
    const int ch0 = quad ^ (lr & 7), ch1 = (4 + quad) ^ (lr & 7);
    const int vkey = tid & 63, vseg = (tid >> 6) * 16;

    float4v oac[2][4];
    float m_reg[2][4], l_reg[2][4];
#pragma unroll
    for (int i = 0; i < 2; i++) {
#pragma unroll
        for (int j = 0; j < 4; j++) oac[i][j] = zf;
#pragma unroll
        for (int rr = 0; rr < 4; rr++) { m_reg[i][rr] = -3e38f; l_reg[i][rr] = 0.f; }
    }

    for (int kb = 0; kb < 16; ++kb) {
        const int s0 = kb * 64;
        __syncthreads();   // prev iter's Ks/Vt reads done
#pragma unroll
        for (int i = 0; i < 2; i++)
            async16(K + (size_t)(b * 1024 + s0 + w * 16 + i * 8 + sr) * kvs + h * 64 + fch * 8,
                    &Ks[(w * 16 + i * 8) * 64]);
        {
            const unsigned short* vp = V + (size_t)(b * 1024 + s0 + vkey) * kvs + h * 64 + vseg;
            ushort8 v0 = *(const ushort8*)vp;
            ushort8 v1 = *(const ushort8*)(vp + 8);
#pragma unroll
            for (int j = 0; j < 8; j++) {
                Vt[vseg + j][vkey] = v0[j];
                Vt[vseg + 8 + j][vkey] = v1[j];
            }
        }
        if (tid < 64)
            madd[tid] = (1.0f - (float)mask[b * 1024 + s0 + tid]) * (-1.25e9f);
        __syncthreads();

        // ---- QK^T ----
        float4v sa[2][4];
#pragma unroll
        for (int j = 0; j < 4; j++) {
            const int krow = j * 16 + lr;
            bf16x8 kf0 = ldsv8(&Ks[krow * 64 + ch0 * 8]);
            bf16x8 kf1 = ldsv8(&Ks[krow * 64 + ch1 * 8]);
            sa[0][j] = __builtin_amdgcn_mfma_f32_16x16x32_bf16(qf[0][0], kf0, zf, 0, 0, 0);
            sa[0][j] = __builtin_amdgcn_mfma_f32_16x16x32_bf16(qf[0][1], kf1, sa[0][j], 0, 0, 0);
            sa[1][j] = __builtin_amdgcn_mfma_f32_16x16x32_bf16(qf[1][0], kf0, zf, 0, 0, 0);
            sa[1][j] = __builtin_amdgcn_mfma_f32_16x16x32_bf16(qf[1][1], kf1, sa[1][j], 0, 0, 0);
        }
#pragma unroll
        for (int j = 0; j < 4; j++) {
            const float ma = madd[j * 16 + lr];
            sa[0][j] = sa[0][j] * 0.015625f + ma;
            sa[1][j] = sa[1][j] * 0.015625f + ma;
        }

        // ---- online softmax (registers + quad shfl) ----
#pragma unroll
        for (int i = 0; i < 2; i++) {
#pragma unroll
            for (int rr = 0; rr < 4; rr++) {
                float rm = fmaxf(fmaxf(sa[i][0][rr], sa[i][1][rr]),
                                 fmaxf(sa[i][2][rr], sa[i][3][rr]));
                rm = fmaxf(rm, __shfl_xor(rm, 1));
                rm = fmaxf(rm, __shfl_xor(rm, 2));
                rm = fmaxf(rm, __shfl_xor(rm, 4));
                rm = fmaxf(rm, __shfl_xor(rm, 8));
                float mnew = fmaxf(m_reg[i][rr], rm);
                float al = __expf(m_reg[i][rr] - mnew);
                float p0 = __expf(sa[i][0][rr] - mnew);
                float p1 = __expf(sa[i][1][rr] - mnew);
                float p2 = __expf(sa[i][2][rr] - mnew);
                float p3 = __expf(sa[i][3][rr] - mnew);
                float rs = p0 + p1 + p2 + p3;
                rs += __shfl_xor(rs, 1);
                rs += __shfl_xor(rs, 2);
                rs += __shfl_xor(rs, 4);
                rs += __shfl_xor(rs, 8);
                l_reg[i][rr] = l_reg[i][rr] * al + rs;
                m_reg[i][rr] = mnew;
                const int row = wm + i * 16 + quad * 4 + rr;
                Pb[row][ 0 + lr] = f2bf1(p0);
                Pb[row][16 + lr] = f2bf1(p1);
                Pb[row][32 + lr] = f2bf1(p2);
                Pb[row][48 + lr] = f2bf1(p3);
                oac[i][0][rr] *= al;
                oac[i][1][rr] *= al;
                oac[i][2][rr] *= al;
                oac[i][3][rr] *= al;
            }
        }
        // Pb rows of this wave written & read by the same wave -> no barrier

        // ---- PV ----
        bf16x8 pf[2][2];
#pragma unroll
        for (int i = 0; i < 2; i++)
#pragma unroll
            for (int c = 0; c < 2; c++)
                pf[i][c] = ldsv8(&Pb[wm + i * 16 + lr][c * 32 + quad * 8]);
#pragma unroll
        for (int j = 0; j < 4; j++) {
            bf16x8 vf0 = ldsv8(&Vt[j * 16 + lr][quad * 8]);
            bf16x8 vf1 = ldsv8(&Vt[j * 16 + lr][32 + quad * 8]);
            oac[0][j] = __builtin_amdgcn_mfma_f32_16x16x32_bf16(pf[0][0], vf0, oac[0][j], 0, 0, 0);
            oac[0][j] = __builtin_amdgcn_mfma_f32_16x16x32_bf16(pf[0][1], vf1, oac[0][j], 0, 0, 0);
            oac[1][j] = __builtin_amdgcn_mfma_f32_16x16x32_bf16(pf[1][0], vf0, oac[1][j], 0, 0, 0);
            oac[1][j] = __builtin_amdgcn_mfma_f32_16x16x32_bf16(pf[1][1], vf1, oac[1][j], 0, 0, 0);
        }
    }

#pragma unroll
    for (int i = 0; i < 2; i++)
#pragma unroll
        for (int rr = 0; rr < 4; rr++) {
            const float inv = 1.0f / l_reg[i][rr];
            const int row = q0 + wm + i * 16 + quad * 4 + rr;
            unsigned short* op = O + (size_t)(b * 1024 + row) * 1024 + h * 64;
#pragma unroll
            for (int j = 0; j < 4; j++)
                op[j * 16 + lr] = f2bf1(oac[i][j][rr] * inv);
        }
}

// ---------------- fused residual-add + LayerNorm (row = 1024) -------------------
__global__ __launch_bounds__(256) void add_ln_kernel(
    const float* __restrict__ X, const float* __restrict__ R,
    const float* __restrict__ g, const float* __restrict__ bb,
    float* __restrict__ outF, unsigned short* __restrict__ outB)
{
    const int row = blockIdx.x, tid = threadIdx.x;
    const float4v* x4 = (const float4v*)(X + (size_t)row * 1024);
    const float4v* r4 = (const float4v*)(R + (size_t)row * 1024);
    float4v z = x4[tid] + r4[tid];
    float s = z.x + z.y + z.z + z.w;
    float sq = z.x * z.x + z.y * z.y + z.z * z.z + z.w * z.w;
#pragma unroll
    for (int off = 32; off > 0; off >>= 1) {
        s += __shfl_down(s, off);
        sq += __shfl_down(sq, off);
    }
    __shared__ float ws[4], wsq[4];
    __shared__ float sm, sr;
    if ((tid & 63) == 0) { ws[tid >> 6] = s; wsq[tid >> 6] = sq; }
    __syncthreads();
    if (tid == 0) {
        float S1 = ws[0] + ws[1] + ws[2] + ws[3];
        float S2 = wsq[0] + wsq[1] + wsq[2] + wsq[3];
        float mean = S1 * (1.0f / 1024.0f);
        float var = S2 * (1.0f / 1024.0f) - mean * mean;
        sm = mean;
        sr = rsqrtf(var + 1e-5f);
    }
    __syncthreads();
    const float mean = sm, rstd = sr;
    const float4v* g4 = (const float4v*)g;
    const float4v* b4 = (const float4v*)bb;
    float4v res = g4[tid] * ((z - mean) * rstd) + b4[tid];
    if (outF) ((float4v*)(outF + (size_t)row * 1024))[tid] = res;
    if (outB) {
        uint2v u = { f2bf2(res.x, res.y), f2bf2(res.z, res.w) };
        *(uint2v*)(outB + (size_t)row * 1024 + tid * 4) = u;
    }
}

// ---------------- transpose + convert: S[R][C] f32 -> D[C][R] bf16 --------------
__device__ __forceinline__ void tconv_body(const float* __restrict__ S,
                                           unsigned short* __restrict__ D,
                                           int R, int C, int r0, int c0)
{
    __shared__ float tile[64][65];
    const int tid = threadIdx.x;
    const int tr = tid >> 4, tc4 = (tid & 15) * 4;
#pragma unroll
    for (int i = 0; i < 4; i++) {
        const int rr = i * 16 + tr;
        *(float4v*)&tile[rr][tc4] = *(const float4v*)(S + (size_t)(r0 + rr) * C + c0 + tc4);
    }
    __syncthreads();
#pragma unroll
    for (int i = 0; i < 4; i++) {
        const int dr = i * 16 + tr;   // dst row = src col
        float v0 = tile[tc4 + 0][dr];
        float v1 = tile[tc4 + 1][dr];
        float v2 = tile[tc4 + 2][dr];
        float v3 = tile[tc4 + 3][dr];
        uint2v u = { f2bf2(v0, v1), f2bf2(v2, v3) };
        *(uint2v*)(D + (size_t)(c0 + dr) * R + r0 + tc4) = u;
    }
}
__global__ __launch_bounds__(256) void transpose_conv(
    const float* __restrict__ S, unsigned short* __restrict__ D, int R, int C)
{
    tconv_body(S, D, R, C, blockIdx.y * 64, blockIdx.x * 64);
}
__global__ __launch_bounds__(256) void transpose8(
    const float* s0, const float* s1, const float* s2, const float* s3,
    const float* s4, const float* s5, const float* s6, const float* s7,
    unsigned short* d0, unsigned short* d1, unsigned short* d2, unsigned short* d3,
    unsigned short* d4, unsigned short* d5, unsigned short* d6, unsigned short* d7)
{
    const float* S;
    unsigned short* D;
    switch (blockIdx.z) {
        case 0: S = s0; D = d0; break;
        case 1: S = s1; D = d1; break;
        case 2: S = s2; D = d2; break;
        case 3: S = s3; D = d3; break;
        case 4: S = s4; D = d4; break;
        case 5: S = s5; D = d5; break;
        case 6: S = s6; D = d6; break;
        default: S = s7; D = d7; break;
    }
    tconv_body(S, D, 1024, 1024, blockIdx.y * 64, blockIdx.x * 64);
}

// ---------------- f32 -> bf16 convert (two buffers of 4M elems) -----------------
__global__ __launch_bounds__(256) void convert_bf16(
    const float* __restrict__ s0, unsigned short* __restrict__ d0,
    const float* __restrict__ s1, unsigned short* __restrict__ d1)
{
    const float* s = blockIdx.y ? s1 : s0;
    unsigned short* d = blockIdx.y ? d1 : d0;
    const size_t i = ((size_t)blockIdx.x * 256 + threadIdx.x) * 4;
    float4v v = *(const float4v*)(s + i);
    uint2v u = { f2bf2(v.x, v.y), f2bf2(v.z, v.w) };
    *(uint2v*)(d + i) = u;
}

// ---------------- concat biases for fused QKV / KV GEMMs ------------------------
__global__ __launch_bounds__(256) void biascat(
    const float* __restrict__ sbq, const float* __restrict__ sbk, const float* __restrict__ sbv,
    const float* __restrict__ cbk, const float* __restrict__ cbv,
    float* __restrict__ bq, float* __restrict__ bc)
{
    const int i = blockIdx.x * 256 + threadIdx.x;
    if (i < 3072)
        bq[i] = i < 1024 ? sbq[i] : (i < 2048 ? sbk[i - 1024] : sbv[i - 2048]);
    else {
        const int j = i - 3072;
        bc[j] = j < 1024 ? cbk[j] : cbv[j - 1024];
    }
}

// --------------------------------------------------------------------------------
extern "C" void kernel_launch(void* const* d_in, const int* in_sizes, int n_in,
                              void* d_out, int out_size, void* d_ws, size_t ws_size,
                              hipStream_t stream)
{
    const float* x     = (const float*)d_in[0];
    const int*   smask = (const int*)d_in[1];
    const float* cx    = (const float*)d_in[2];
    const int*   cmask = (const int*)d_in[3];
    const float* sWq = (const float*)d_in[5],  *sbq = (const float*)d_in[6];
    const float* sWk = (const float*)d_in[7],  *sbk = (const float*)d_in[8];
    const float* sWv = (const float*)d_in[9],  *sbv = (const float*)d_in[10];
    const float* sWo = (const float*)d_in[11], *sbo = (const float*)d_in[12];
    const float* cWq = (const float*)d_in[13], *cbq = (const float*)d_in[14];
    const float* cWk = (const float*)d_in[15], *cbk = (const float*)d_in[16];
    const float* cWv = (const float*)d_in[17], *cbv = (const float*)d_in[18];
    const float* cWo = (const float*)d_in[19], *cbo = (const float*)d_in[20];
    const float* g   = (const float*)d_in[21], *bb  = (const float*)d_in[22];
    const float* W1  = (const float*)d_in[23], *b1  = (const float*)d_in[24];
    const float* W2  = (const float*)d_in[25], *b2  = (const float*)d_in[26];
    float* out = (float*)d_out;

    const size_t MB = 1024 * 1024;
    unsigned char* ws = (unsigned char*)d_ws;
    // bf16 activation buffers
    unsigned short* xb   = (unsigned short*)(ws + 0 * MB);    // 8 MB
    unsigned short* cxb  = (unsigned short*)(ws + 8 * MB);    // 8 MB
    unsigned short* SANb = (unsigned short*)(ws + 16 * MB);   // 8 MB
    unsigned short* QKV  = (unsigned short*)(ws + 24 * MB);   // 24 MB [4096][3072]
    unsigned short* CQ   = (unsigned short*)(ws + 24 * MB);   // 8 MB  (after QKV dead)
    unsigned short* CKV  = (unsigned short*)(ws + 32 * MB);   // 16 MB [4096][2048]
    unsigned short* T    = (unsigned short*)(ws + 48 * MB);   // 8 MB
    float*          Af   = (float*)(ws + 56 * MB);            // 16 MB
    float*          HH   = (float*)(ws + 72 * MB);            // 16 MB
    unsigned short* HHb  = (unsigned short*)(ws + 88 * MB);   // 8 MB
    // transposed bf16 weights
    unsigned short* WtQKV = (unsigned short*)(ws + 96 * MB);  // 6 MB [3072][1024]
    unsigned short* WtCKV = (unsigned short*)(ws + 102 * MB); // 4 MB [2048][1024]
    unsigned short* WtSWO = (unsigned short*)(ws + 106 * MB); // 2 MB
    unsigned short* WtCWQ = (unsigned short*)(ws + 108 * MB); // 2 MB
    unsigned short* WtCWO = (unsigned short*)(ws + 110 * MB); // 2 MB
    unsigned short* WtW1  = (unsigned short*)(ws + 112 * MB); // 8 MB [4096][1024]
    unsigned short* WtW2  = (unsigned short*)(ws + 120 * MB); // 8 MB [1024][4096]
    float* biasQ = (float*)(ws + 128 * MB);                   // 12 KB
    float* biasC = (float*)(ws + 128 * MB + 16 * 1024);       // 8 KB
    unsigned short* MID = (unsigned short*)(ws + 0 * MB);     // 32 MB, overlaps xb/cxb/SANb (dead)

    dim3 blk(256);

    // ---- conversions (once per call) ----
    convert_bf16<<<dim3(4096, 2), blk, 0, stream>>>(x, xb, cx, cxb);
    transpose8<<<dim3(16, 16, 8), blk, 0, stream>>>(
        sWq, sWk, sWv, cWk, cWv, sWo, cWq, cWo,
        WtQKV, WtQKV + 1024 * 1024, WtQKV + 2 * 1024 * 1024,
        WtCKV, WtCKV + 1024 * 1024,
        WtSWO, WtCWQ, WtCWO);
    transpose_conv<<<dim3(64, 16), blk, 0, stream>>>(W1, WtW1, 1024, 4096);
    transpose_conv<<<dim3(16, 64), blk, 0, stream>>>(W2, WtW2, 4096, 1024);
    biascat<<<20, blk, 0, stream>>>(sbq, sbk, sbv, cbk, cbv, biasQ, biasC);

    // ---- self attention ----
    gemm_bt<0, 1><<<dim3(24, 32), blk, 0, stream>>>(xb, WtQKV, biasQ, QKV, 4096, 3072, 1024);
    attn_mfma<<<dim3(8, 16, 4), blk, 0, stream>>>(QKV, 3072, QKV + 1024, QKV + 2048, 3072, smask, T);
    gemm_bt<0, 0><<<dim3(8, 32), blk, 0, stream>>>(T, WtSWO, sbo, Af, 4096, 1024, 1024);
    add_ln_kernel<<<4096, blk, 0, stream>>>(Af, x, g, bb, nullptr, SANb);

    // ---- cross attention (residual = ORIGINAL x) ----
    gemm_bt<0, 1><<<dim3(8, 32), blk, 0, stream>>>(SANb, WtCWQ, cbq, CQ, 4096, 1024, 1024);
    gemm_bt<0, 1><<<dim3(16, 32), blk, 0, stream>>>(cxb, WtCKV, biasC, CKV, 4096, 2048, 1024);
    attn_mfma<<<dim3(8, 16, 4), blk, 0, stream>>>(CQ, 1024, CKV, CKV + 1024, 2048, cmask, T);
    gemm_bt<0, 0><<<dim3(8, 32), blk, 0, stream>>>(T, WtCWO, cbo, Af, 4096, 1024, 1024);
    add_ln_kernel<<<4096, blk, 0, stream>>>(Af, x, g, bb, HH, HHb);

    // ---- FFN ----
    gemm_bt<1, 1><<<dim3(32, 32), blk, 0, stream>>>(HHb, WtW1, b1, MID, 4096, 4096, 1024);
    gemm_bt<0, 0><<<dim3(8, 32), blk, 0, stream>>>(MID, WtW2, b2, Af, 4096, 1024, 4096);
    add_ln_kernel<<<4096, blk, 0, stream>>>(Af, HH, g, bb, out, nullptr);
}

// Round 4
// 582.257 us; speedup vs baseline: 2.7574x; 1.0281x over previous
//
#include <hip/hip_runtime.h>
#include <hip/hip_bf16.h>

// Decoder block: self-MHA -> add+LN -> cross-MHA -> add+LN(resid=orig x) -> FFN -> add+LN
// B=4 S=1024 H=1024 NH=16 d=64.
// bf16 MFMA GEMMs with global_load_lds(16B) + XOR-swizzled LDS. GEMMs at 1-2
// blocks/CU use an explicit double-buffered pipeline (raw s_barrier + vmcnt(8))
// to hide staging latency that 1-block/CU occupancy cannot (m114/m139 evidence).
// ORDER=1 grids put A-sharers on one XCD (id%8 = M-tile) for L2 reuse.

typedef float float4v __attribute__((ext_vector_type(4)));
typedef __bf16 bf16x8 __attribute__((ext_vector_type(8)));
typedef unsigned short ushort8 __attribute__((ext_vector_type(8)));
typedef unsigned int uint2v __attribute__((ext_vector_type(2)));

__device__ __forceinline__ unsigned short f2bf1(float f) {
    unsigned u = __builtin_bit_cast(unsigned, f);
    u += 0x7fffu + ((u >> 16) & 1u);
    return (unsigned short)(u >> 16);
}
__device__ __forceinline__ unsigned f2bf2(float lo, float hi) {
    unsigned a = __builtin_bit_cast(unsigned, lo);
    a += 0x7fffu + ((a >> 16) & 1u);
    unsigned b = __builtin_bit_cast(unsigned, hi);
    b += 0x7fffu + ((b >> 16) & 1u);
    return (a >> 16) | (b & 0xffff0000u);
}
__device__ __forceinline__ bf16x8 ldsv8(const unsigned short* p) {
    return __builtin_bit_cast(bf16x8, *(const ushort8*)p);
}
// async global->LDS, 16B per lane; LDS dest = wave-uniform base + lane*16
__device__ __forceinline__ void async16(const unsigned short* g, unsigned short* l) {
    __builtin_amdgcn_global_load_lds(
        (const __attribute__((address_space(1))) unsigned int*)(g),
        (__attribute__((address_space(3))) unsigned int*)(l),
        16, 0, 0);
}

// ---------------- GEMM: C[M,N] = A[M,K] @ Wt[N,K]^T + bias ---------------------
// A, Wt bf16. 128x128 tile, BK=64, 4 waves 2x2 of 64x64, 16x16x32 MFMA.
// DBUF=1: double-buffered LDS, raw s_barrier + s_waitcnt vmcnt(8) pipeline.
// ORDER=1: blockIdx.x indexes M-tiles (XCD co-location of A-sharers).
template <int RELU, int OUT_BF16, int DBUF, int ORDER>
__global__ __launch_bounds__(256) void gemm_bt(
    const unsigned short* __restrict__ A, const unsigned short* __restrict__ Bt,
    const float* __restrict__ bias, void* __restrict__ Cout,
    int M, int N, int K)
{
    __shared__ __align__(16) unsigned short As[(DBUF ? 2 : 1) * 128 * 64];
    __shared__ __align__(16) unsigned short Bs[(DBUF ? 2 : 1) * 128 * 64];

    const int tid = threadIdx.x;
    const int m0 = (ORDER ? blockIdx.x : blockIdx.y) * 128;
    const int n0 = (ORDER ? blockIdx.y : blockIdx.x) * 128;
    const int w = tid >> 6, lane = tid & 63;
    const int lr = lane & 15, quad = lane >> 4;
    const int wm = (w >> 1) * 64, wn = (w & 1) * 64;

    const int sr = lane >> 3, sc = lane & 7;
    const int fch = sc ^ sr;                       // swizzled source chunk
    const unsigned short* Ag = A + (size_t)(m0 + w * 32 + sr) * K + fch * 8;
    const unsigned short* Bg = Bt + (size_t)(n0 + w * 32 + sr) * K + fch * 8;

    float4v acc[4][4];
#pragma unroll
    for (int i = 0; i < 4; i++)
#pragma unroll
        for (int j = 0; j < 4; j++) acc[i][j] = 0.f;

    const int ch0 = quad ^ (lr & 7);
    const int ch1 = (4 + quad) ^ (lr & 7);

    auto issue = [&](int buf, int k0) {
        unsigned short* Al = &As[buf * (128 * 64) + (w * 32) * 64];
        unsigned short* Bl = &Bs[buf * (128 * 64) + (w * 32) * 64];
#pragma unroll
        for (int i = 0; i < 4; i++) {
            async16(Ag + (size_t)(i * 8) * K + k0, Al + (i * 8) * 64);
            async16(Bg + (size_t)(i * 8) * K + k0, Bl + (i * 8) * 64);
        }
    };
    auto compute = [&](int buf) {
        const unsigned short* Ab = &As[buf * (128 * 64)];
        const unsigned short* Bb = &Bs[buf * (128 * 64)];
#pragma unroll
        for (int kk = 0; kk < 2; kk++) {
            const int ch = kk ? ch1 : ch0;
            bf16x8 af[4], bf[4];
#pragma unroll
            for (int i = 0; i < 4; i++) {
                af[i] = ldsv8(&Ab[(wm + i * 16 + lr) * 64 + ch * 8]);
                bf[i] = ldsv8(&Bb[(wn + i * 16 + lr) * 64 + ch * 8]);
            }
#pragma unroll
            for (int i = 0; i < 4; i++)
#pragma unroll
                for (int j = 0; j < 4; j++)
                    acc[i][j] = __builtin_amdgcn_mfma_f32_16x16x32_bf16(af[i], bf[j], acc[i][j], 0, 0, 0);
        }
    };

    if (DBUF) {
        const int NIT = K >> 6;
        issue(0, 0);
        for (int it = 0; it < NIT; ++it) {
            const int nxt = it + 1;
            if (nxt < NIT) {
                issue(nxt & 1, nxt << 6);
                __builtin_amdgcn_sched_barrier(0);
                __builtin_amdgcn_s_waitcnt(0x0F78);   // vmcnt(8): iter-it loads done
            } else {
                __builtin_amdgcn_sched_barrier(0);
                __builtin_amdgcn_s_waitcnt(0x0F70);   // vmcnt(0)
            }
            __builtin_amdgcn_s_barrier();
            __builtin_amdgcn_sched_barrier(0);
            compute(it & 1);
            __builtin_amdgcn_sched_barrier(0);
            __builtin_amdgcn_s_barrier();             // readers done before buf reuse
            __builtin_amdgcn_sched_barrier(0);
        }
    } else {
        for (int k0 = 0; k0 < K; k0 += 64) {
            issue(0, k0);
            __syncthreads();
            compute(0);
            __syncthreads();
        }
    }

#pragma unroll
    for (int j = 0; j < 4; j++) {
        const int col = n0 + wn + j * 16 + lr;
        const float bv = bias[col];
#pragma unroll
        for (int i = 0; i < 4; i++) {
            const int row0 = m0 + wm + i * 16 + quad * 4;
#pragma unroll
            for (int r = 0; r < 4; r++) {
                float v = acc[i][j][r] + bv;
                if (RELU) v = fmaxf(v, 0.f);
                if (OUT_BF16)
                    ((unsigned short*)Cout)[(size_t)(row0 + r) * N + col] = f2bf1(v);
                else
                    ((float*)Cout)[(size_t)(row0 + r) * N + col] = v;
            }
        }
    }
}

// ---------------- MFMA flash attention (bf16 in/out) ----------------------------
__global__ __launch_bounds__(256) void attn_mfma(
    const unsigned short* __restrict__ Q, int qs,
    const unsigned short* __restrict__ K, const unsigned short* __restrict__ V, int kvs,
    const int* __restrict__ mask, unsigned short* __restrict__ O)
{
    __shared__ __align__(16) unsigned short Ks[64 * 64];   // [key][d], swizzled chunks
    __shared__ __align__(16) unsigned short Vt[64][72];    // [d][key]
    __shared__ __align__(16) unsigned short Pb[128][72];   // [q][key] bf16 probs
    __shared__ float madd[64];

    const int tid = threadIdx.x;
    const int b = blockIdx.z, h = blockIdx.y, q0 = blockIdx.x * 128;
    const int w = tid >> 6, lane = tid & 63;
    const int lr = lane & 15, quad = lane >> 4;
    const int wm = w * 32;
    const float4v zf = {0.f, 0.f, 0.f, 0.f};

    bf16x8 qf[2][2];
#pragma unroll
    for (int i = 0; i < 2; i++)
#pragma unroll
        for (int c = 0; c < 2; c++)
            qf[i][c] = ldsv8(Q + (size_t)(b * 1024 + q0 + wm + i * 16 + lr) * qs
                             + h * 64 + c * 32 + quad * 8);

    const int sr = lane >> 3, sc = lane & 7;
    const int fch = sc ^ sr;
    const int ch0 = quad ^ (lr & 7), ch1 = (4 + quad) ^ (lr & 7);
    const int vkey = tid & 63, vseg = (tid >> 6) * 16;

    float4v oac[2][4];
    float m_reg[2][4], l_reg[2][4];
#pragma unroll
    for (int i = 0; i < 2; i++) {
#pragma unroll
        for (int j = 0; j < 4; j++) oac[i][j] = zf;
#pragma unroll
        for (int rr = 0; rr < 4; rr++) { m_reg[i][rr] = -3e38f; l_reg[i][rr] = 0.f; }
    }

    for (int kb = 0; kb < 16; ++kb) {
        const int s0 = kb * 64;
        __syncthreads();
#pragma unroll
        for (int i = 0; i < 2; i++)
            async16(K + (size_t)(b * 1024 + s0 + w * 16 + i * 8 + sr) * kvs + h * 64 + fch * 8,
                    &Ks[(w * 16 + i * 8) * 64]);
        {
            const unsigned short* vp = V + (size_t)(b * 1024 + s0 + vkey) * kvs + h * 64 + vseg;
            ushort8 v0 = *(const ushort8*)vp;
            ushort8 v1 = *(const ushort8*)(vp + 8);
#pragma unroll
            for (int j = 0; j < 8; j++) {
                Vt[vseg + j][vkey] = v0[j];
                Vt[vseg + 8 + j][vkey] = v1[j];
            }
        }
        if (tid < 64)
            madd[tid] = (1.0f - (float)mask[b * 1024 + s0 + tid]) * (-1.25e9f);
        __syncthreads();

        float4v sa[2][4];
#pragma unroll
        for (int j = 0; j < 4; j++) {
            const int krow = j * 16 + lr;
            bf16x8 kf0 = ldsv8(&Ks[krow * 64 + ch0 * 8]);
            bf16x8 kf1 = ldsv8(&Ks[krow * 64 + ch1 * 8]);
            sa[0][j] = __builtin_amdgcn_mfma_f32_16x16x32_bf16(qf[0][0], kf0, zf, 0, 0, 0);
            sa[0][j] = __builtin_amdgcn_mfma_f32_16x16x32_bf16(qf[0][1], kf1, sa[0][j], 0, 0, 0);
            sa[1][j] = __builtin_amdgcn_mfma_f32_16x16x32_bf16(qf[1][0], kf0, zf, 0, 0, 0);
            sa[1][j] = __builtin_amdgcn_mfma_f32_16x16x32_bf16(qf[1][1], kf1, sa[1][j], 0, 0, 0);
        }
#pragma unroll
        for (int j = 0; j < 4; j++) {
            const float ma = madd[j * 16 + lr];
            sa[0][j] = sa[0][j] * 0.015625f + ma;
            sa[1][j] = sa[1][j] * 0.015625f + ma;
        }

#pragma unroll
        for (int i = 0; i < 2; i++) {
#pragma unroll
            for (int rr = 0; rr < 4; rr++) {
                float rm = fmaxf(fmaxf(sa[i][0][rr], sa[i][1][rr]),
                                 fmaxf(sa[i][2][rr], sa[i][3][rr]));
                rm = fmaxf(rm, __shfl_xor(rm, 1));
                rm = fmaxf(rm, __shfl_xor(rm, 2));
                rm = fmaxf(rm, __shfl_xor(rm, 4));
                rm = fmaxf(rm, __shfl_xor(rm, 8));
                float mnew = fmaxf(m_reg[i][rr], rm);
                float al = __expf(m_reg[i][rr] - mnew);
                float p0 = __expf(sa[i][0][rr] - mnew);
                float p1 = __expf(sa[i][1][rr] - mnew);
                float p2 = __expf(sa[i][2][rr] - mnew);
                float p3 = __expf(sa[i][3][rr] - mnew);
                float rs = p0 + p1 + p2 + p3;
                rs += __shfl_xor(rs, 1);
                rs += __shfl_xor(rs, 2);
                rs += __shfl_xor(rs, 4);
                rs += __shfl_xor(rs, 8);
                l_reg[i][rr] = l_reg[i][rr] * al + rs;
                m_reg[i][rr] = mnew;
                const int row = wm + i * 16 + quad * 4 + rr;
                Pb[row][ 0 + lr] = f2bf1(p0);
                Pb[row][16 + lr] = f2bf1(p1);
                Pb[row][32 + lr] = f2bf1(p2);
                Pb[row][48 + lr] = f2bf1(p3);
                oac[i][0][rr] *= al;
                oac[i][1][rr] *= al;
                oac[i][2][rr] *= al;
                oac[i][3][rr] *= al;
            }
        }

        bf16x8 pf[2][2];
#pragma unroll
        for (int i = 0; i < 2; i++)
#pragma unroll
            for (int c = 0; c < 2; c++)
                pf[i][c] = ldsv8(&Pb[wm + i * 16 + lr][c * 32 + quad * 8]);
#pragma unroll
        for (int j = 0; j < 4; j++) {
            bf16x8 vf0 = ldsv8(&Vt[j * 16 + lr][quad * 8]);
            bf16x8 vf1 = ldsv8(&Vt[j * 16 + lr][32 + quad * 8]);
            oac[0][j] = __builtin_amdgcn_mfma_f32_16x16x32_bf16(pf[0][0], vf0, oac[0][j], 0, 0, 0);
            oac[0][j] = __builtin_amdgcn_mfma_f32_16x16x32_bf16(pf[0][1], vf1, oac[0][j], 0, 0, 0);
            oac[1][j] = __builtin_amdgcn_mfma_f32_16x16x32_bf16(pf[1][0], vf0, oac[1][j], 0, 0, 0);
            oac[1][j] = __builtin_amdgcn_mfma_f32_16x16x32_bf16(pf[1][1], vf1, oac[1][j], 0, 0, 0);
        }
    }

#pragma unroll
    for (int i = 0; i < 2; i++)
#pragma unroll
        for (int rr = 0; rr < 4; rr++) {
            const float inv = 1.0f / l_reg[i][rr];
            const int row = q0 + wm + i * 16 + quad * 4 + rr;
            unsigned short* op = O + (size_t)(b * 1024 + row) * 1024 + h * 64;
#pragma unroll
            for (int j = 0; j < 4; j++)
                op[j * 16 + lr] = f2bf1(oac[i][j][rr] * inv);
        }
}

// ---------------- fused residual-add + LayerNorm (row = 1024) -------------------
__global__ __launch_bounds__(256) void add_ln_kernel(
    const float* __restrict__ X, const float* __restrict__ R,
    const float* __restrict__ g, const float* __restrict__ bb,
    float* __restrict__ outF, unsigned short* __restrict__ outB)
{
    const int row = blockIdx.x, tid = threadIdx.x;
    const float4v* x4 = (const float4v*)(X + (size_t)row * 1024);
    const float4v* r4 = (const float4v*)(R + (size_t)row * 1024);
    float4v z = x4[tid] + r4[tid];
    float s = z.x + z.y + z.z + z.w;
    float sq = z.x * z.x + z.y * z.y + z.z * z.z + z.w * z.w;
#pragma unroll
    for (int off = 32; off > 0; off >>= 1) {
        s += __shfl_down(s, off);
        sq += __shfl_down(sq, off);
    }
    __shared__ float ws[4], wsq[4];
    __shared__ float sm, sr;
    if ((tid & 63) == 0) { ws[tid >> 6] = s; wsq[tid >> 6] = sq; }
    __syncthreads();
    if (tid == 0) {
        float S1 = ws[0] + ws[1] + ws[2] + ws[3];
        float S2 = wsq[0] + wsq[1] + wsq[2] + wsq[3];
        float mean = S1 * (1.0f / 1024.0f);
        float var = S2 * (1.0f / 1024.0f) - mean * mean;
        sm = mean;
        sr = rsqrtf(var + 1e-5f);
    }
    __syncthreads();
    const float mean = sm, rstd = sr;
    const float4v* g4 = (const float4v*)g;
    const float4v* b4 = (const float4v*)bb;
    float4v res = g4[tid] * ((z - mean) * rstd) + b4[tid];
    if (outF) ((float4v*)(outF + (size_t)row * 1024))[tid] = res;
    if (outB) {
        uint2v u = { f2bf2(res.x, res.y), f2bf2(res.z, res.w) };
        *(uint2v*)(outB + (size_t)row * 1024 + tid * 4) = u;
    }
}

// ---------------- transpose + convert: S[R][C] f32 -> D[C][R] bf16 --------------
__device__ __forceinline__ void tconv_body(const float* __restrict__ S,
                                           unsigned short* __restrict__ D,
                                           int R, int C, int r0, int c0)
{
    __shared__ float tile[64][65];
    const int tid = threadIdx.x;
    const int tr = tid >> 4, tc4 = (tid & 15) * 4;
#pragma unroll
    for (int i = 0; i < 4; i++) {
        const int rr = i * 16 + tr;
        *(float4v*)&tile[rr][tc4] = *(const float4v*)(S + (size_t)(r0 + rr) * C + c0 + tc4);
    }
    __syncthreads();
#pragma unroll
    for (int i = 0; i < 4; i++) {
        const int dr = i * 16 + tr;   // dst row = src col
        float v0 = tile[tc4 + 0][dr];
        float v1 = tile[tc4 + 1][dr];
        float v2 = tile[tc4 + 2][dr];
        float v3 = tile[tc4 + 3][dr];
        uint2v u = { f2bf2(v0, v1), f2bf2(v2, v3) };
        *(uint2v*)(D + (size_t)(c0 + dr) * R + r0 + tc4) = u;
    }
}
__global__ __launch_bounds__(256) void transpose_conv(
    const float* __restrict__ S, unsigned short* __restrict__ D, int R, int C)
{
    tconv_body(S, D, R, C, blockIdx.y * 64, blockIdx.x * 64);
}
__global__ __launch_bounds__(256) void transpose8(
    const float* s0, const float* s1, const float* s2, const float* s3,
    const float* s4, const float* s5, const float* s6, const float* s7,
    unsigned short* d0, unsigned short* d1, unsigned short* d2, unsigned short* d3,
    unsigned short* d4, unsigned short* d5, unsigned short* d6, unsigned short* d7)
{
    const float* S;
    unsigned short* D;
    switch (blockIdx.z) {
        case 0: S = s0; D = d0; break;
        case 1: S = s1; D = d1; break;
        case 2: S = s2; D = d2; break;
        case 3: S = s3; D = d3; break;
        case 4: S = s4; D = d4; break;
        case 5: S = s5; D = d5; break;
        case 6: S = s6; D = d6; break;
        default: S = s7; D = d7; break;
    }
    tconv_body(S, D, 1024, 1024, blockIdx.y * 64, blockIdx.x * 64);
}

// ---------------- f32 -> bf16 convert (two buffers of 4M elems) -----------------
__global__ __launch_bounds__(256) void convert_bf16(
    const float* __restrict__ s0, unsigned short* __restrict__ d0,
    const float* __restrict__ s1, unsigned short* __restrict__ d1)
{
    const float* s = blockIdx.y ? s1 : s0;
    unsigned short* d = blockIdx.y ? d1 : d0;
    const size_t i = ((size_t)blockIdx.x * 256 + threadIdx.x) * 4;
    float4v v = *(const float4v*)(s + i);
    uint2v u = { f2bf2(v.x, v.y), f2bf2(v.z, v.w) };
    *(uint2v*)(d + i) = u;
}

// ---------------- concat biases for fused QKV / KV GEMMs ------------------------
__global__ __launch_bounds__(256) void biascat(
    const float* __restrict__ sbq, const float* __restrict__ sbk, const float* __restrict__ sbv,
    const float* __restrict__ cbk, const float* __restrict__ cbv,
    float* __restrict__ bq, float* __restrict__ bc)
{
    const int i = blockIdx.x * 256 + threadIdx.x;
    if (i < 3072)
        bq[i] = i < 1024 ? sbq[i] : (i < 2048 ? sbk[i - 1024] : sbv[i - 2048]);
    else {
        const int j = i - 3072;
        bc[j] = j < 1024 ? cbk[j] : cbv[j - 1024];
    }
}

// --------------------------------------------------------------------------------
extern "C" void kernel_launch(void* const* d_in, const int* in_sizes, int n_in,
                              void* d_out, int out_size, void* d_ws, size_t ws_size,
                              hipStream_t stream)
{
    const float* x     = (const float*)d_in[0];
    const int*   smask = (const int*)d_in[1];
    const float* cx    = (const float*)d_in[2];
    const int*   cmask = (const int*)d_in[3];
    const float* sWq = (const float*)d_in[5],  *sbq = (const float*)d_in[6];
    const float* sWk = (const float*)d_in[7],  *sbk = (const float*)d_in[8];
    const float* sWv = (const float*)d_in[9],  *sbv = (const float*)d_in[10];
    const float* sWo = (const float*)d_in[11], *sbo = (const float*)d_in[12];
    const float* cWq = (const float*)d_in[13], *cbq = (const float*)d_in[14];
    const float* cWk = (const float*)d_in[15], *cbk = (const float*)d_in[16];
    const float* cWv = (const float*)d_in[17], *cbv = (const float*)d_in[18];
    const float* cWo = (const float*)d_in[19], *cbo = (const float*)d_in[20];
    const float* g   = (const float*)d_in[21], *bb  = (const float*)d_in[22];
    const float* W1  = (const float*)d_in[23], *b1  = (const float*)d_in[24];
    const float* W2  = (const float*)d_in[25], *b2  = (const float*)d_in[26];
    float* out = (float*)d_out;

    const size_t MB = 1024 * 1024;
    unsigned char* ws = (unsigned char*)d_ws;
    unsigned short* xb   = (unsigned short*)(ws + 0 * MB);    // 8 MB
    unsigned short* cxb  = (unsigned short*)(ws + 8 * MB);    // 8 MB
    unsigned short* SANb = (unsigned short*)(ws + 16 * MB);   // 8 MB
    unsigned short* QKV  = (unsigned short*)(ws + 24 * MB);   // 24 MB [4096][3072]
    unsigned short* CQ   = (unsigned short*)(ws + 24 * MB);   // 8 MB  (after QKV dead)
    unsigned short* CKV  = (unsigned short*)(ws + 32 * MB);   // 16 MB [4096][2048]
    unsigned short* T    = (unsigned short*)(ws + 48 * MB);   // 8 MB
    float*          Af   = (float*)(ws + 56 * MB);            // 16 MB
    float*          HH   = (float*)(ws + 72 * MB);            // 16 MB
    unsigned short* HHb  = (unsigned short*)(ws + 88 * MB);   // 8 MB
    unsigned short* WtQKV = (unsigned short*)(ws + 96 * MB);  // 6 MB [3072][1024]
    unsigned short* WtCKV = (unsigned short*)(ws + 102 * MB); // 4 MB [2048][1024]
    unsigned short* WtSWO = (unsigned short*)(ws + 106 * MB); // 2 MB
    unsigned short* WtCWQ = (unsigned short*)(ws + 108 * MB); // 2 MB
    unsigned short* WtCWO = (unsigned short*)(ws + 110 * MB); // 2 MB
    unsigned short* WtW1  = (unsigned short*)(ws + 112 * MB); // 8 MB [4096][1024]
    unsigned short* WtW2  = (unsigned short*)(ws + 120 * MB); // 8 MB [1024][4096]
    float* biasQ = (float*)(ws + 128 * MB);                   // 12 KB
    float* biasC = (float*)(ws + 128 * MB + 16 * 1024);       // 8 KB
    unsigned short* MID = (unsigned short*)(ws + 0 * MB);     // 32 MB, overlaps xb/cxb/SANb (dead)

    dim3 blk(256);

    // ---- conversions (once per call) ----
    convert_bf16<<<dim3(4096, 2), blk, 0, stream>>>(x, xb, cx, cxb);
    transpose8<<<dim3(16, 16, 8), blk, 0, stream>>>(
        sWq, sWk, sWv, cWk, cWv, sWo, cWq, cWo,
        WtQKV, WtQKV + 1024 * 1024, WtQKV + 2 * 1024 * 1024,
        WtCKV, WtCKV + 1024 * 1024,
        WtSWO, WtCWQ, WtCWO);
    transpose_conv<<<dim3(64, 16), blk, 0, stream>>>(W1, WtW1, 1024, 4096);
    transpose_conv<<<dim3(16, 64), blk, 0, stream>>>(W2, WtW2, 4096, 1024);
    biascat<<<20, blk, 0, stream>>>(sbq, sbk, sbv, cbk, cbv, biasQ, biasC);

    // ---- self attention ----
    gemm_bt<0, 1, 0, 1><<<dim3(32, 24), blk, 0, stream>>>(xb, WtQKV, biasQ, QKV, 4096, 3072, 1024);
    attn_mfma<<<dim3(8, 16, 4), blk, 0, stream>>>(QKV, 3072, QKV + 1024, QKV + 2048, 3072, smask, T);
    gemm_bt<0, 0, 1, 1><<<dim3(32, 8), blk, 0, stream>>>(T, WtSWO, sbo, Af, 4096, 1024, 1024);
    add_ln_kernel<<<4096, blk, 0, stream>>>(Af, x, g, bb, nullptr, SANb);

    // ---- cross attention (residual = ORIGINAL x) ----
    gemm_bt<0, 1, 1, 1><<<dim3(32, 8), blk, 0, stream>>>(SANb, WtCWQ, cbq, CQ, 4096, 1024, 1024);
    gemm_bt<0, 1, 1, 1><<<dim3(32, 16), blk, 0, stream>>>(cxb, WtCKV, biasC, CKV, 4096, 2048, 1024);
    attn_mfma<<<dim3(8, 16, 4), blk, 0, stream>>>(CQ, 1024, CKV, CKV + 1024, 2048, cmask, T);
    gemm_bt<0, 0, 1, 1><<<dim3(32, 8), blk, 0, stream>>>(T, WtCWO, cbo, Af, 4096, 1024, 1024);
    add_ln_kernel<<<4096, blk, 0, stream>>>(Af, x, g, bb, HH, HHb);

    // ---- FFN ----
    gemm_bt<1, 1, 0, 0><<<dim3(32, 32), blk, 0, stream>>>(HHb, WtW1, b1, MID, 4096, 4096, 1024);
    gemm_bt<0, 0, 1, 1><<<dim3(32, 8), blk, 0, stream>>>(MID, WtW2, b2, Af, 4096, 1024, 4096);
    add_ln_kernel<<<4096, blk, 0, stream>>>(Af, HH, g, bb, out, nullptr);
}

// Round 5
// 528.460 us; speedup vs baseline: 3.0381x; 1.1018x over previous
//
#include <hip/hip_runtime.h>
#include <hip/hip_bf16.h>

// Decoder block: self-MHA -> add+LN -> cross-MHA -> add+LN(resid=orig x) -> FFN -> add+LN
// B=4 S=1024 H=1024 NH=16 d=64.
// bf16 MFMA GEMMs, global_load_lds(16B) + XOR-swizzled LDS. 1-2 block/CU GEMMs use
// dbuf pipeline (s_barrier + vmcnt(8)); O-proj/FFN2 use split-K=2 with partial-sum
// reduction fused into the add+LN kernel. Attention: 64-row q-tiles (4 blocks/CU),
// permuted-key P/V LDS layout (pos=(k&15)*4+(k>>4)) -> packed b64/b32 LDS writes,
// XOR-swizzled stride-64 rows (0-conflict pattern measured in R3 GEMM).

typedef float float4v __attribute__((ext_vector_type(4)));
typedef __bf16 bf16x8 __attribute__((ext_vector_type(8)));
typedef unsigned short ushort8 __attribute__((ext_vector_type(8)));
typedef unsigned int uint2v __attribute__((ext_vector_type(2)));

__device__ __forceinline__ unsigned short f2bf1(float f) {
    unsigned u = __builtin_bit_cast(unsigned, f);
    u += 0x7fffu + ((u >> 16) & 1u);
    return (unsigned short)(u >> 16);
}
__device__ __forceinline__ unsigned f2bf2(float lo, float hi) {
    unsigned a = __builtin_bit_cast(unsigned, lo);
    a += 0x7fffu + ((a >> 16) & 1u);
    unsigned b = __builtin_bit_cast(unsigned, hi);
    b += 0x7fffu + ((b >> 16) & 1u);
    return (a >> 16) | (b & 0xffff0000u);
}
__device__ __forceinline__ bf16x8 ldsv8(const unsigned short* p) {
    return __builtin_bit_cast(bf16x8, *(const ushort8*)p);
}
// async global->LDS, 16B per lane; LDS dest = wave-uniform base + lane*16
__device__ __forceinline__ void async16(const unsigned short* g, unsigned short* l) {
    __builtin_amdgcn_global_load_lds(
        (const __attribute__((address_space(1))) unsigned int*)(g),
        (__attribute__((address_space(3))) unsigned int*)(l),
        16, 0, 0);
}

// ---------------- GEMM: C[M,N] = A[M,K] @ Wt[N,K]^T (+ bias) -------------------
// 128x128 tile, BK=64, 4 waves 2x2 of 64x64, 16x16x32 MFMA. DBUF=1: explicit
// double-buffer with raw s_barrier + vmcnt(8). ORDER=1: blockIdx.x = M-tile.
// gridDim.z > 1: split-K; slice z computes K/gridDim.z and writes Cout + z*M*N.
template <int RELU, int OUT_BF16, int DBUF, int ORDER>
__global__ __launch_bounds__(256) void gemm_bt(
    const unsigned short* __restrict__ A, const unsigned short* __restrict__ Bt,
    const float* __restrict__ bias, void* __restrict__ Cout,
    int M, int N, int K)
{
    __shared__ __align__(16) unsigned short As[(DBUF ? 2 : 1) * 128 * 64];
    __shared__ __align__(16) unsigned short Bs[(DBUF ? 2 : 1) * 128 * 64];

    const int tid = threadIdx.x;
    const int m0 = (ORDER ? blockIdx.x : blockIdx.y) * 128;
    const int n0 = (ORDER ? blockIdx.y : blockIdx.x) * 128;
    const int KL = K / gridDim.z;
    const int kbase = blockIdx.z * KL;
    const int w = tid >> 6, lane = tid & 63;
    const int lr = lane & 15, quad = lane >> 4;
    const int wm = (w >> 1) * 64, wn = (w & 1) * 64;

    const int sr = lane >> 3, sc = lane & 7;
    const int fch = sc ^ sr;                       // swizzled source chunk
    const unsigned short* Ag = A + (size_t)(m0 + w * 32 + sr) * K + kbase + fch * 8;
    const unsigned short* Bg = Bt + (size_t)(n0 + w * 32 + sr) * K + kbase + fch * 8;

    float4v acc[4][4];
#pragma unroll
    for (int i = 0; i < 4; i++)
#pragma unroll
        for (int j = 0; j < 4; j++) acc[i][j] = 0.f;

    const int ch0 = quad ^ (lr & 7);
    const int ch1 = (4 + quad) ^ (lr & 7);

    auto issue = [&](int buf, int k0) {
        unsigned short* Al = &As[buf * (128 * 64) + (w * 32) * 64];
        unsigned short* Bl = &Bs[buf * (128 * 64) + (w * 32) * 64];
#pragma unroll
        for (int i = 0; i < 4; i++) {
            async16(Ag + (size_t)(i * 8) * K + k0, Al + (i * 8) * 64);
            async16(Bg + (size_t)(i * 8) * K + k0, Bl + (i * 8) * 64);
        }
    };
    auto compute = [&](int buf) {
        const unsigned short* Ab = &As[buf * (128 * 64)];
        const unsigned short* Bb = &Bs[buf * (128 * 64)];
#pragma unroll
        for (int kk = 0; kk < 2; kk++) {
            const int ch = kk ? ch1 : ch0;
            bf16x8 af[4], bf[4];
#pragma unroll
            for (int i = 0; i < 4; i++) {
                af[i] = ldsv8(&Ab[(wm + i * 16 + lr) * 64 + ch * 8]);
                bf[i] = ldsv8(&Bb[(wn + i * 16 + lr) * 64 + ch * 8]);
            }
#pragma unroll
            for (int i = 0; i < 4; i++)
#pragma unroll
                for (int j = 0; j < 4; j++)
                    acc[i][j] = __builtin_amdgcn_mfma_f32_16x16x32_bf16(af[i], bf[j], acc[i][j], 0, 0, 0);
        }
    };

    if (DBUF) {
        const int NIT = KL >> 6;
        issue(0, 0);
        for (int it = 0; it < NIT; ++it) {
            const int nxt = it + 1;
            if (nxt < NIT) {
                issue(nxt & 1, nxt << 6);
                __builtin_amdgcn_sched_barrier(0);
                __builtin_amdgcn_s_waitcnt(0x0F78);   // vmcnt(8): iter-it loads done
            } else {
                __builtin_amdgcn_sched_barrier(0);
                __builtin_amdgcn_s_waitcnt(0x0F70);   // vmcnt(0)
            }
            __builtin_amdgcn_s_barrier();
            __builtin_amdgcn_sched_barrier(0);
            compute(it & 1);
            __builtin_amdgcn_sched_barrier(0);
            __builtin_amdgcn_s_barrier();             // readers done before buf reuse
            __builtin_amdgcn_sched_barrier(0);
        }
    } else {
        for (int k0 = 0; k0 < KL; k0 += 64) {
            issue(0, k0);
            __syncthreads();
            compute(0);
            __syncthreads();
        }
    }

#pragma unroll
    for (int j = 0; j < 4; j++) {
        const int col = n0 + wn + j * 16 + lr;
        const float bv = bias ? bias[col] : 0.f;
#pragma unroll
        for (int i = 0; i < 4; i++) {
            const int row0 = m0 + wm + i * 16 + quad * 4;
#pragma unroll
            for (int r = 0; r < 4; r++) {
                float v = acc[i][j][r] + bv;
                if (RELU) v = fmaxf(v, 0.f);
                if (OUT_BF16)
                    ((unsigned short*)Cout)[(size_t)(row0 + r) * N + col] = f2bf1(v);
                else
                    ((float*)Cout)[(size_t)blockIdx.z * M * N + (size_t)(row0 + r) * N + col] = v;
            }
        }
    }
}

// ---------------- MFMA flash attention (bf16 in/out) ----------------------------
// One block per (b, h, 64 q-rows); 4 waves x 16 q-rows. Key-permuted P/V LDS
// layout: key k stored at pos=(k&15)*4+(k>>4); P & Vt agree so contraction order
// is irrelevant. All LDS rows stride-64 shorts, 16B chunks XOR-swizzled by row&7.
__global__ __launch_bounds__(256) void attn_mfma(
    const unsigned short* __restrict__ Q, int qs,
    const unsigned short* __restrict__ K, const unsigned short* __restrict__ V, int kvs,
    const int* __restrict__ mask, unsigned short* __restrict__ O)
{
    __shared__ __align__(16) unsigned short Ks[64 * 64];   // [key][d]   (natural keys)
    __shared__ __align__(16) unsigned short Vt[64 * 64];   // [d][pos]   (permuted keys)
    __shared__ __align__(16) unsigned short Pb[64 * 64];   // [q][pos]   (permuted keys)
    __shared__ float madd[64];

    const int tid = threadIdx.x;
    const int b = blockIdx.z, h = blockIdx.y, q0 = blockIdx.x * 64;
    const int w = tid >> 6, lane = tid & 63;
    const int lr = lane & 15, quad = lane >> 4;
    const float4v zf = {0.f, 0.f, 0.f, 0.f};

    // Q fragments (A-layout) for this wave's 16 q-rows, kept in registers
    bf16x8 qf[2];
#pragma unroll
    for (int c = 0; c < 2; c++)
        qf[c] = ldsv8(Q + (size_t)(b * 1024 + q0 + w * 16 + lr) * qs
                      + h * 64 + c * 32 + quad * 8);

    const int sr = lane >> 3, sc = lane & 7;
    const int fch = sc ^ sr;
    const int ch0 = quad ^ (lr & 7), ch1 = (4 + quad) ^ (lr & 7);

    // V staging assignment: thread handles key-pair (vkb, vkb+16), 8 d's
    const int vk = tid & 15, vh = tid >> 7;
    const int vkb = vk + vh * 32;
    const int vseg = ((tid >> 4) & 7) * 8;
    const int pospair = vk * 4 + vh * 2;                // pos(vkb), pos(vkb)+1
    const int vchunk = pospair >> 3, voff = pospair & 7;

    float4v oac[4];
    float m_reg[4], l_reg[4];
#pragma unroll
    for (int j = 0; j < 4; j++) oac[j] = zf;
#pragma unroll
    for (int rr = 0; rr < 4; rr++) { m_reg[rr] = -3e38f; l_reg[rr] = 0.f; }

    for (int kb = 0; kb < 16; ++kb) {
        const int s0 = kb * 64;
        __syncthreads();   // prev iter's Ks/Vt reads done
#pragma unroll
        for (int i = 0; i < 2; i++)
            async16(K + (size_t)(b * 1024 + s0 + w * 16 + i * 8 + sr) * kvs + h * 64 + fch * 8,
                    &Ks[(w * 16 + i * 8) * 64]);
        {
            const unsigned short* vp = V + (size_t)(b * 1024 + s0 + vkb) * kvs + h * 64 + vseg;
            ushort8 v0 = *(const ushort8*)vp;
            ushort8 v1 = *(const ushort8*)(vp + (size_t)16 * kvs);
#pragma unroll
            for (int j = 0; j < 8; j++) {
                const int row = vseg + j;
                const int schv = vchunk ^ (row & 7);
                *(unsigned*)&Vt[row * 64 + schv * 8 + voff] =
                    (unsigned)v0[j] | ((unsigned)v1[j] << 16);
            }
        }
        if (tid < 64)
            madd[tid] = (1.0f - (float)mask[b * 1024 + s0 + tid]) * (-1.25e9f);
        __syncthreads();

        // ---- QK^T: 16 q-rows x 64 keys per wave ----
        float4v sa[4];
#pragma unroll
        for (int j = 0; j < 4; j++) {
            const int krow = j * 16 + lr;
            bf16x8 kf0 = ldsv8(&Ks[krow * 64 + ch0 * 8]);
            bf16x8 kf1 = ldsv8(&Ks[krow * 64 + ch1 * 8]);
            sa[j] = __builtin_amdgcn_mfma_f32_16x16x32_bf16(qf[0], kf0, zf, 0, 0, 0);
            sa[j] = __builtin_amdgcn_mfma_f32_16x16x32_bf16(qf[1], kf1, sa[j], 0, 0, 0);
        }
#pragma unroll
        for (int j = 0; j < 4; j++)
            sa[j] = sa[j] * 0.015625f + madd[j * 16 + lr];

        // ---- online softmax (registers + quad shfl); packed b64 P stores ----
#pragma unroll
        for (int rr = 0; rr < 4; rr++) {
            float rm = fmaxf(fmaxf(sa[0][rr], sa[1][rr]), fmaxf(sa[2][rr], sa[3][rr]));
            rm = fmaxf(rm, __shfl_xor(rm, 1));
            rm = fmaxf(rm, __shfl_xor(rm, 2));
            rm = fmaxf(rm, __shfl_xor(rm, 4));
            rm = fmaxf(rm, __shfl_xor(rm, 8));
            const float mnew = fmaxf(m_reg[rr], rm);
            const float al = __expf(m_reg[rr] - mnew);
            const float p0 = __expf(sa[0][rr] - mnew);
            const float p1 = __expf(sa[1][rr] - mnew);
            const float p2 = __expf(sa[2][rr] - mnew);
            const float p3 = __expf(sa[3][rr] - mnew);
            float rs = p0 + p1 + p2 + p3;
            rs += __shfl_xor(rs, 1);
            rs += __shfl_xor(rs, 2);
            rs += __shfl_xor(rs, 4);
            rs += __shfl_xor(rs, 8);
            l_reg[rr] = l_reg[rr] * al + rs;
            m_reg[rr] = mnew;
            // keys {lr,16+lr,32+lr,48+lr} -> pos {4lr..4lr+3}: one b64 write
            const int row = w * 16 + quad * 4 + rr;
            const int schp = (lr >> 1) ^ (row & 7);
            uint2v pk = { f2bf2(p0, p1), f2bf2(p2, p3) };
            *(uint2v*)&Pb[row * 64 + schp * 8 + (lr & 1) * 4] = pk;
            oac[0][rr] *= al;
            oac[1][rr] *= al;
            oac[2][rr] *= al;
            oac[3][rr] *= al;
        }
        // Pb rows of this wave written & read by the same wave -> no barrier

        // ---- PV: O += P @ V (both in permuted-key pos order) ----
        bf16x8 pf0 = ldsv8(&Pb[(w * 16 + lr) * 64 + ch0 * 8]);
        bf16x8 pf1 = ldsv8(&Pb[(w * 16 + lr) * 64 + ch1 * 8]);
#pragma unroll
        for (int j = 0; j < 4; j++) {
            bf16x8 vf0 = ldsv8(&Vt[(j * 16 + lr) * 64 + ch0 * 8]);
            bf16x8 vf1 = ldsv8(&Vt[(j * 16 + lr) * 64 + ch1 * 8]);
            oac[j] = __builtin_amdgcn_mfma_f32_16x16x32_bf16(pf0, vf0, oac[j], 0, 0, 0);
            oac[j] = __builtin_amdgcn_mfma_f32_16x16x32_bf16(pf1, vf1, oac[j], 0, 0, 0);
        }
    }

#pragma unroll
    for (int rr = 0; rr < 4; rr++) {
        const float inv = 1.0f / l_reg[rr];
        const int row = q0 + w * 16 + quad * 4 + rr;
        unsigned short* op = O + (size_t)(b * 1024 + row) * 1024 + h * 64;
#pragma unroll
        for (int j = 0; j < 4; j++)
            op[j * 16 + lr] = f2bf1(oac[j][rr] * inv);
    }
}

// ------------- fused partial-sum + bias + residual-add + LayerNorm --------------
// z = sum_{p<nparts} P[p*PSTRIDE + row] + lbias + R[row];  out = g*(z-mu)/sd + b
#define PSTRIDE ((size_t)4096 * 1024)
__global__ __launch_bounds__(256) void add_ln_kernel(
    const float* __restrict__ P, int nparts, const float* __restrict__ lbias,
    const float* __restrict__ R,
    const float* __restrict__ g, const float* __restrict__ bb,
    float* __restrict__ outF, unsigned short* __restrict__ outB)
{
    const int row = blockIdx.x, tid = threadIdx.x;
    float4v z = ((const float4v*)(R + (size_t)row * 1024))[tid];
    for (int p = 0; p < nparts; ++p)
        z += ((const float4v*)(P + p * PSTRIDE + (size_t)row * 1024))[tid];
    if (lbias) z += ((const float4v*)lbias)[tid];
    float s = z.x + z.y + z.z + z.w;
    float sq = z.x * z.x + z.y * z.y + z.z * z.z + z.w * z.w;
#pragma unroll
    for (int off = 32; off > 0; off >>= 1) {
        s += __shfl_down(s, off);
        sq += __shfl_down(sq, off);
    }
    __shared__ float ws[4], wsq[4];
    __shared__ float sm, sr;
    if ((tid & 63) == 0) { ws[tid >> 6] = s; wsq[tid >> 6] = sq; }
    __syncthreads();
    if (tid == 0) {
        float S1 = ws[0] + ws[1] + ws[2] + ws[3];
        float S2 = wsq[0] + wsq[1] + wsq[2] + wsq[3];
        float mean = S1 * (1.0f / 1024.0f);
        float var = S2 * (1.0f / 1024.0f) - mean * mean;
        sm = mean;
        sr = rsqrtf(var + 1e-5f);
    }
    __syncthreads();
    const float mean = sm, rstd = sr;
    const float4v* g4 = (const float4v*)g;
    const float4v* b4 = (const float4v*)bb;
    float4v res = g4[tid] * ((z - mean) * rstd) + b4[tid];
    if (outF) ((float4v*)(outF + (size_t)row * 1024))[tid] = res;
    if (outB) {
        uint2v u = { f2bf2(res.x, res.y), f2bf2(res.z, res.w) };
        *(uint2v*)(outB + (size_t)row * 1024 + tid * 4) = u;
    }
}

// ---------------- transpose + convert: S[R][C] f32 -> D[C][R] bf16 --------------
__device__ __forceinline__ void tconv_body(const float* __restrict__ S,
                                           unsigned short* __restrict__ D,
                                           int R, int C, int r0, int c0)
{
    __shared__ float tile[64][65];
    const int tid = threadIdx.x;
    const int tr = tid >> 4, tc4 = (tid & 15) * 4;
#pragma unroll
    for (int i = 0; i < 4; i++) {
        const int rr = i * 16 + tr;
        *(float4v*)&tile[rr][tc4] = *(const float4v*)(S + (size_t)(r0 + rr) * C + c0 + tc4);
    }
    __syncthreads();
#pragma unroll
    for (int i = 0; i < 4; i++) {
        const int dr = i * 16 + tr;   // dst row = src col
        float v0 = tile[tc4 + 0][dr];
        float v1 = tile[tc4 + 1][dr];
        float v2 = tile[tc4 + 2][dr];
        float v3 = tile[tc4 + 3][dr];
        uint2v u = { f2bf2(v0, v1), f2bf2(v2, v3) };
        *(uint2v*)(D + (size_t)(c0 + dr) * R + r0 + tc4) = u;
    }
}
__global__ __launch_bounds__(256) void transpose_conv(
    const float* __restrict__ S, unsigned short* __restrict__ D, int R, int C)
{
    tconv_body(S, D, R, C, blockIdx.y * 64, blockIdx.x * 64);
}
__global__ __launch_bounds__(256) void transpose8(
    const float* s0, const float* s1, const float* s2, const float* s3,
    const float* s4, const float* s5, const float* s6, const float* s7,
    unsigned short* d0, unsigned short* d1, unsigned short* d2, unsigned short* d3,
    unsigned short* d4, unsigned short* d5, unsigned short* d6, unsigned short* d7)
{
    const float* S;
    unsigned short* D;
    switch (blockIdx.z) {
        case 0: S = s0; D = d0; break;
        case 1: S = s1; D = d1; break;
        case 2: S = s2; D = d2; break;
        case 3: S = s3; D = d3; break;
        case 4: S = s4; D = d4; break;
        case 5: S = s5; D = d5; break;
        case 6: S = s6; D = d6; break;
        default: S = s7; D = d7; break;
    }
    tconv_body(S, D, 1024, 1024, blockIdx.y * 64, blockIdx.x * 64);
}

// ---------------- f32 -> bf16 convert (two buffers of 4M elems) -----------------
__global__ __launch_bounds__(256) void convert_bf16(
    const float* __restrict__ s0, unsigned short* __restrict__ d0,
    const float* __restrict__ s1, unsigned short* __restrict__ d1)
{
    const float* s = blockIdx.y ? s1 : s0;
    unsigned short* d = blockIdx.y ? d1 : d0;
    const size_t i = ((size_t)blockIdx.x * 256 + threadIdx.x) * 4;
    float4v v = *(const float4v*)(s + i);
    uint2v u = { f2bf2(v.x, v.y), f2bf2(v.z, v.w) };
    *(uint2v*)(d + i) = u;
}

// ---------------- concat biases for fused QKV / KV GEMMs ------------------------
__global__ __launch_bounds__(256) void biascat(
    const float* __restrict__ sbq, const float* __restrict__ sbk, const float* __restrict__ sbv,
    const float* __restrict__ cbk, const float* __restrict__ cbv,
    float* __restrict__ bq, float* __restrict__ bc)
{
    const int i = blockIdx.x * 256 + threadIdx.x;
    if (i < 3072)
        bq[i] = i < 1024 ? sbq[i] : (i < 2048 ? sbk[i - 1024] : sbv[i - 2048]);
    else {
        const int j = i - 3072;
        bc[j] = j < 1024 ? cbk[j] : cbv[j - 1024];
    }
}

// --------------------------------------------------------------------------------
extern "C" void kernel_launch(void* const* d_in, const int* in_sizes, int n_in,
                              void* d_out, int out_size, void* d_ws, size_t ws_size,
                              hipStream_t stream)
{
    const float* x     = (const float*)d_in[0];
    const int*   smask = (const int*)d_in[1];
    const float* cx    = (const float*)d_in[2];
    const int*   cmask = (const int*)d_in[3];
    const float* sWq = (const float*)d_in[5],  *sbq = (const float*)d_in[6];
    const float* sWk = (const float*)d_in[7],  *sbk = (const float*)d_in[8];
    const float* sWv = (const float*)d_in[9],  *sbv = (const float*)d_in[10];
    const float* sWo = (const float*)d_in[11], *sbo = (const float*)d_in[12];
    const float* cWq = (const float*)d_in[13], *cbq = (const float*)d_in[14];
    const float* cWk = (const float*)d_in[15], *cbk = (const float*)d_in[16];
    const float* cWv = (const float*)d_in[17], *cbv = (const float*)d_in[18];
    const float* cWo = (const float*)d_in[19], *cbo = (const float*)d_in[20];
    const float* g   = (const float*)d_in[21], *bb  = (const float*)d_in[22];
    const float* W1  = (const float*)d_in[23], *b1  = (const float*)d_in[24];
    const float* W2  = (const float*)d_in[25], *b2  = (const float*)d_in[26];
    float* out = (float*)d_out;

    const size_t MB = 1024 * 1024;
    unsigned char* ws = (unsigned char*)d_ws;
    // early-phase activations (all dead before FFN1 writes MID @0..32)
    unsigned short* xb   = (unsigned short*)(ws + 0 * MB);    // 8 MB
    unsigned short* cxb  = (unsigned short*)(ws + 8 * MB);    // 8 MB
    unsigned short* SANb = (unsigned short*)(ws + 16 * MB);   // 8 MB
    unsigned short* CQ   = (unsigned short*)(ws + 24 * MB);   // 8 MB
    unsigned short* MID  = (unsigned short*)(ws + 0 * MB);    // 32 MB (FFN phase)
    unsigned short* QKV  = (unsigned short*)(ws + 32 * MB);   // 24 MB [4096][3072]
    unsigned short* CKV  = (unsigned short*)(ws + 32 * MB);   // 16 MB (QKV dead)
    unsigned short* T    = (unsigned short*)(ws + 56 * MB);   // 8 MB
    float*          P    = (float*)(ws + 64 * MB);            // 2x16 MB split-K partials
    float*          HH   = (float*)(ws + 96 * MB);            // 16 MB
    unsigned short* HHb  = (unsigned short*)(ws + 112 * MB);  // 8 MB
    unsigned short* WtQKV = (unsigned short*)(ws + 120 * MB); // 6 MB [3072][1024]
    unsigned short* WtCKV = (unsigned short*)(ws + 126 * MB); // 4 MB [2048][1024]
    unsigned short* WtSWO = (unsigned short*)(ws + 130 * MB); // 2 MB
    unsigned short* WtCWQ = (unsigned short*)(ws + 132 * MB); // 2 MB
    unsigned short* WtCWO = (unsigned short*)(ws + 134 * MB); // 2 MB
    unsigned short* WtW1  = (unsigned short*)(ws + 136 * MB); // 8 MB [4096][1024]
    unsigned short* WtW2  = (unsigned short*)(ws + 144 * MB); // 8 MB [1024][4096]
    float* biasQ = (float*)(ws + 152 * MB);                   // 12 KB
    float* biasC = (float*)(ws + 152 * MB + 16 * 1024);       // 8 KB

    dim3 blk(256);

    // ---- conversions (once per call) ----
    convert_bf16<<<dim3(4096, 2), blk, 0, stream>>>(x, xb, cx, cxb);
    transpose8<<<dim3(16, 16, 8), blk, 0, stream>>>(
        sWq, sWk, sWv, cWk, cWv, sWo, cWq, cWo,
        WtQKV, WtQKV + 1024 * 1024, WtQKV + 2 * 1024 * 1024,
        WtCKV, WtCKV + 1024 * 1024,
        WtSWO, WtCWQ, WtCWO);
    transpose_conv<<<dim3(64, 16), blk, 0, stream>>>(W1, WtW1, 1024, 4096);
    transpose_conv<<<dim3(16, 64), blk, 0, stream>>>(W2, WtW2, 4096, 1024);
    biascat<<<20, blk, 0, stream>>>(sbq, sbk, sbv, cbk, cbv, biasQ, biasC);

    // ---- self attention ----
    gemm_bt<0, 1, 0, 1><<<dim3(32, 24), blk, 0, stream>>>(xb, WtQKV, biasQ, QKV, 4096, 3072, 1024);
    attn_mfma<<<dim3(16, 16, 4), blk, 0, stream>>>(QKV, 3072, QKV + 1024, QKV + 2048, 3072, smask, T);
    gemm_bt<0, 0, 1, 1><<<dim3(32, 8, 2), blk, 0, stream>>>(T, WtSWO, nullptr, P, 4096, 1024, 1024);
    add_ln_kernel<<<4096, blk, 0, stream>>>(P, 2, sbo, x, g, bb, nullptr, SANb);

    // ---- cross attention (residual = ORIGINAL x) ----
    gemm_bt<0, 1, 1, 1><<<dim3(32, 8), blk, 0, stream>>>(SANb, WtCWQ, cbq, CQ, 4096, 1024, 1024);
    gemm_bt<0, 1, 1, 1><<<dim3(32, 16), blk, 0, stream>>>(cxb, WtCKV, biasC, CKV, 4096, 2048, 1024);
    attn_mfma<<<dim3(16, 16, 4), blk, 0, stream>>>(CQ, 1024, CKV, CKV + 1024, 2048, cmask, T);
    gemm_bt<0, 0, 1, 1><<<dim3(32, 8, 2), blk, 0, stream>>>(T, WtCWO, nullptr, P, 4096, 1024, 1024);
    add_ln_kernel<<<4096, blk, 0, stream>>>(P, 2, cbo, x, g, bb, HH, HHb);

    // ---- FFN ----
    gemm_bt<1, 1, 0, 0><<<dim3(32, 32), blk, 0, stream>>>(HHb, WtW1, b1, MID, 4096, 4096, 1024);
    gemm_bt<0, 0, 1, 1><<<dim3(32, 8, 2), blk, 0, stream>>>(MID, WtW2, nullptr, P, 4096, 1024, 4096);
    add_ln_kernel<<<4096, blk, 0, stream>>>(P, 2, b2, HH, g, bb, out, nullptr);
}

// Round 6
// 490.210 us; speedup vs baseline: 3.2751x; 1.0780x over previous
//
#include <hip/hip_runtime.h>
#include <hip/hip_bf16.h>

// Decoder block: self-MHA -> add+LN -> cross-MHA -> add+LN(resid=orig x) -> FFN -> add+LN
// B=4 S=1024 H=1024 NH=16 d=64.
// bf16 MFMA GEMMs, global_load_lds(16B) + XOR-swizzled LDS; dbuf pipeline for
// low-occupancy GEMMs; split-K=2 + LN-fused reduction for O-proj/FFN2.
// Attention: no-max flash (logits qk/64 are tiny; mask is multiplicative),
// l-sum deferred to epilogue (zero shfl in loop), V pre-transposed+pos-permuted
// by the producing GEMM epilogue so attention stages V^T via async16 like K.

typedef float float4v __attribute__((ext_vector_type(4)));
typedef __bf16 bf16x8 __attribute__((ext_vector_type(8)));
typedef unsigned short ushort8 __attribute__((ext_vector_type(8)));
typedef unsigned int uint2v __attribute__((ext_vector_type(2)));

#define VBIG (1 << 29)

__device__ __forceinline__ unsigned short f2bf1(float f) {
    unsigned u = __builtin_bit_cast(unsigned, f);
    u += 0x7fffu + ((u >> 16) & 1u);
    return (unsigned short)(u >> 16);
}
__device__ __forceinline__ unsigned f2bf2(float lo, float hi) {
    unsigned a = __builtin_bit_cast(unsigned, lo);
    a += 0x7fffu + ((a >> 16) & 1u);
    unsigned b = __builtin_bit_cast(unsigned, hi);
    b += 0x7fffu + ((b >> 16) & 1u);
    return (a >> 16) | (b & 0xffff0000u);
}
__device__ __forceinline__ bf16x8 ldsv8(const unsigned short* p) {
    return __builtin_bit_cast(bf16x8, *(const ushort8*)p);
}
// async global->LDS, 16B per lane; LDS dest = wave-uniform base + lane*16
__device__ __forceinline__ void async16(const unsigned short* g, unsigned short* l) {
    __builtin_amdgcn_global_load_lds(
        (const __attribute__((address_space(1))) unsigned int*)(g),
        (__attribute__((address_space(3))) unsigned int*)(l),
        16, 0, 0);
}

// ---------------- GEMM: C[M,N] = A[M,K] @ Wt[N,K]^T (+ bias) -------------------
// 128x128 tile, BK=64, 4 waves 2x2 of 64x64, 16x16x32 MFMA.
// qcols: output cols < qcols are scaled by 1/64 (Q pre-scale, block-uniform).
// vcol0: blocks with n0 >= vcol0 write V^T pos-permuted into VTout instead:
//   VTout[((b*16+h)*64+d)*1024 + (t&~63) + pos(t&63)], pos(k)=(k&15)*4+(k>>4).
// gridDim.z>1: split-K, f32 partials at Cout + z*M*ldc.
template <int RELU, int OUT_BF16, int DBUF, int ORDER>
__global__ __launch_bounds__(256) void gemm_bt(
    const unsigned short* __restrict__ A, const unsigned short* __restrict__ Bt,
    const float* __restrict__ bias, void* __restrict__ Cout,
    int M, int N, int K, int ldc, int qcols, int vcol0,
    unsigned short* __restrict__ VTout)
{
    __shared__ __align__(16) unsigned short As[(DBUF ? 2 : 1) * 128 * 64];
    __shared__ __align__(16) unsigned short Bs[(DBUF ? 2 : 1) * 128 * 64];

    const int tid = threadIdx.x;
    const int m0 = (ORDER ? blockIdx.x : blockIdx.y) * 128;
    const int n0 = (ORDER ? blockIdx.y : blockIdx.x) * 128;
    const int KL = K / gridDim.z;
    const int kbase = blockIdx.z * KL;
    const int w = tid >> 6, lane = tid & 63;
    const int lr = lane & 15, quad = lane >> 4;
    const int wm = (w >> 1) * 64, wn = (w & 1) * 64;

    const int sr = lane >> 3, sc = lane & 7;
    const int fch = sc ^ sr;                       // swizzled source chunk
    const unsigned short* Ag = A + (size_t)(m0 + w * 32 + sr) * K + kbase + fch * 8;
    const unsigned short* Bg = Bt + (size_t)(n0 + w * 32 + sr) * K + kbase + fch * 8;

    float4v acc[4][4];
#pragma unroll
    for (int i = 0; i < 4; i++)
#pragma unroll
        for (int j = 0; j < 4; j++) acc[i][j] = 0.f;

    const int ch0 = quad ^ (lr & 7);
    const int ch1 = (4 + quad) ^ (lr & 7);

    auto issue = [&](int buf, int k0) {
        unsigned short* Al = &As[buf * (128 * 64) + (w * 32) * 64];
        unsigned short* Bl = &Bs[buf * (128 * 64) + (w * 32) * 64];
#pragma unroll
        for (int i = 0; i < 4; i++) {
            async16(Ag + (size_t)(i * 8) * K + k0, Al + (i * 8) * 64);
            async16(Bg + (size_t)(i * 8) * K + k0, Bl + (i * 8) * 64);
        }
    };
    auto compute = [&](int buf) {
        const unsigned short* Ab = &As[buf * (128 * 64)];
        const unsigned short* Bb = &Bs[buf * (128 * 64)];
#pragma unroll
        for (int kk = 0; kk < 2; kk++) {
            const int ch = kk ? ch1 : ch0;
            bf16x8 af[4], bf[4];
#pragma unroll
            for (int i = 0; i < 4; i++) {
                af[i] = ldsv8(&Ab[(wm + i * 16 + lr) * 64 + ch * 8]);
                bf[i] = ldsv8(&Bb[(wn + i * 16 + lr) * 64 + ch * 8]);
            }
#pragma unroll
            for (int i = 0; i < 4; i++)
#pragma unroll
                for (int j = 0; j < 4; j++)
                    acc[i][j] = __builtin_amdgcn_mfma_f32_16x16x32_bf16(af[i], bf[j], acc[i][j], 0, 0, 0);
        }
    };

    if (DBUF) {
        const int NIT = KL >> 6;
        issue(0, 0);
        for (int it = 0; it < NIT; ++it) {
            const int nxt = it + 1;
            if (nxt < NIT) {
                issue(nxt & 1, nxt << 6);
                __builtin_amdgcn_sched_barrier(0);
                __builtin_amdgcn_s_waitcnt(0x0F78);   // vmcnt(8): iter-it loads done
            } else {
                __builtin_amdgcn_sched_barrier(0);
                __builtin_amdgcn_s_waitcnt(0x0F70);   // vmcnt(0)
            }
            __builtin_amdgcn_s_barrier();
            __builtin_amdgcn_sched_barrier(0);
            compute(it & 1);
            __builtin_amdgcn_sched_barrier(0);
            __builtin_amdgcn_s_barrier();             // readers done before buf reuse
            __builtin_amdgcn_sched_barrier(0);
        }
    } else {
        for (int k0 = 0; k0 < KL; k0 += 64) {
            issue(0, k0);
            __syncthreads();
            compute(0);
            __syncthreads();
        }
    }

    if (n0 >= vcol0) {
        // ---- V^T pos-permuted epilogue (token k -> pos 16*quad + 4*r + i) ----
        const int crel = n0 - vcol0 + wn;             // multiple of 64
        const int hh = crel >> 6;
        const int bidx = (m0 + wm) >> 10;
        const int tbase = ((m0 + wm) & 1023) + quad * 16;
#pragma unroll
        for (int j = 0; j < 4; j++) {
            const float bv = bias ? bias[n0 + wn + j * 16 + lr] : 0.f;
            const int d = j * 16 + lr;
            unsigned short* vp = VTout + ((size_t)(bidx * 16 + hh) * 64 + d) * 1024 + tbase;
#pragma unroll
            for (int r = 0; r < 4; r++) {
                uint2v u = { f2bf2(acc[0][j][r] + bv, acc[1][j][r] + bv),
                             f2bf2(acc[2][j][r] + bv, acc[3][j][r] + bv) };
                *(uint2v*)(vp + r * 4) = u;
            }
        }
        return;
    }

    const float qs = (n0 < qcols) ? 0.015625f : 1.0f;
#pragma unroll
    for (int j = 0; j < 4; j++) {
        const int col = n0 + wn + j * 16 + lr;
        const float bv = bias ? bias[col] : 0.f;
#pragma unroll
        for (int i = 0; i < 4; i++) {
            const int row0 = m0 + wm + i * 16 + quad * 4;
#pragma unroll
            for (int r = 0; r < 4; r++) {
                float v = (acc[i][j][r] + bv) * qs;
                if (RELU) v = fmaxf(v, 0.f);
                if (OUT_BF16)
                    ((unsigned short*)Cout)[(size_t)(row0 + r) * ldc + col] = f2bf1(v);
                else
                    ((float*)Cout)[(size_t)blockIdx.z * M * ldc + (size_t)(row0 + r) * ldc + col] = v;
            }
        }
    }
}

// ---------------- MFMA flash attention (bf16 in/out), no-max variant -----------
// One block per (b, h, 128 q-rows); 4 waves x 32 q-rows. Q pre-scaled by 1/64.
// p = exp(qk') * maskf (exact for 0/1 masks; logits tiny -> no overflow).
// l-sum: lane-local partials, reduced once in epilogue. V^T comes pre-transposed
// and pos-permuted from the producing GEMM -> staged via async16 like K.
__global__ __launch_bounds__(256) void attn_mfma(
    const unsigned short* __restrict__ Q, int qs,
    const unsigned short* __restrict__ K, int kvs,
    const unsigned short* __restrict__ VT,     // [(b*16+h)*64+d][1024], pos-permuted
    const float* __restrict__ maskf,           // [b][1024]
    unsigned short* __restrict__ O)
{
    __shared__ __align__(16) unsigned short Ks[64 * 64];   // [key][d]
    __shared__ __align__(16) unsigned short Vt[64 * 64];   // [d][pos]
    __shared__ __align__(16) unsigned short Pb[128 * 64];  // [q][pos]

    const int tid = threadIdx.x;
    const int b = blockIdx.z, h = blockIdx.y, q0 = blockIdx.x * 128;
    const int w = tid >> 6, lane = tid & 63;
    const int lr = lane & 15, quad = lane >> 4;
    const int wm = w * 32;
    const float4v zf = {0.f, 0.f, 0.f, 0.f};

    // Q fragments (A-layout) for this wave's 32 q-rows, kept in registers
    bf16x8 qf[2][2];
#pragma unroll
    for (int i = 0; i < 2; i++)
#pragma unroll
        for (int c = 0; c < 2; c++)
            qf[i][c] = ldsv8(Q + (size_t)(b * 1024 + q0 + wm + i * 16 + lr) * qs
                             + h * 64 + c * 32 + quad * 8);

    const int sr = lane >> 3, sc = lane & 7;
    const int fch = sc ^ sr;
    const int ch0 = quad ^ (lr & 7), ch1 = (4 + quad) ^ (lr & 7);
    const unsigned short* VTb = VT + (size_t)(b * 16 + h) * 64 * 1024;

    float4v oac[2][4];
    float lsum[2][4];
#pragma unroll
    for (int i = 0; i < 2; i++) {
#pragma unroll
        for (int j = 0; j < 4; j++) oac[i][j] = zf;
#pragma unroll
        for (int rr = 0; rr < 4; rr++) lsum[i][rr] = 0.f;
    }

    for (int kb = 0; kb < 16; ++kb) {
        const int s0 = kb * 64;
        __syncthreads();   // prev iter's Ks/Vt reads done
#pragma unroll
        for (int i = 0; i < 2; i++) {
            async16(K + (size_t)(b * 1024 + s0 + w * 16 + i * 8 + sr) * kvs + h * 64 + fch * 8,
                    &Ks[(w * 16 + i * 8) * 64]);
            async16(VTb + (size_t)(w * 16 + i * 8 + sr) * 1024 + s0 + fch * 8,
                    &Vt[(w * 16 + i * 8) * 64]);
        }
        float mf[4];
#pragma unroll
        for (int j = 0; j < 4; j++)
            mf[j] = maskf[b * 1024 + s0 + j * 16 + lr];
        __syncthreads();

        // ---- QK^T: 32 q-rows x 64 keys per wave ----
        float4v sa[2][4];
#pragma unroll
        for (int j = 0; j < 4; j++) {
            const int krow = j * 16 + lr;
            bf16x8 kf0 = ldsv8(&Ks[krow * 64 + ch0 * 8]);
            bf16x8 kf1 = ldsv8(&Ks[krow * 64 + ch1 * 8]);
            sa[0][j] = __builtin_amdgcn_mfma_f32_16x16x32_bf16(qf[0][0], kf0, zf, 0, 0, 0);
            sa[0][j] = __builtin_amdgcn_mfma_f32_16x16x32_bf16(qf[0][1], kf1, sa[0][j], 0, 0, 0);
            sa[1][j] = __builtin_amdgcn_mfma_f32_16x16x32_bf16(qf[1][0], kf0, zf, 0, 0, 0);
            sa[1][j] = __builtin_amdgcn_mfma_f32_16x16x32_bf16(qf[1][1], kf1, sa[1][j], 0, 0, 0);
        }

        // ---- p = exp(s) * mask; lane-local l partials; packed b64 P stores ----
#pragma unroll
        for (int i = 0; i < 2; i++) {
#pragma unroll
            for (int rr = 0; rr < 4; rr++) {
                const float p0 = __expf(sa[i][0][rr]) * mf[0];
                const float p1 = __expf(sa[i][1][rr]) * mf[1];
                const float p2 = __expf(sa[i][2][rr]) * mf[2];
                const float p3 = __expf(sa[i][3][rr]) * mf[3];
                lsum[i][rr] += (p0 + p1) + (p2 + p3);
                // keys {lr,16+lr,32+lr,48+lr} -> pos {4lr..4lr+3}: one b64 write
                const int row = wm + i * 16 + quad * 4 + rr;
                const int schp = (lr >> 1) ^ (row & 7);
                uint2v pk = { f2bf2(p0, p1), f2bf2(p2, p3) };
                *(uint2v*)&Pb[row * 64 + schp * 8 + (lr & 1) * 4] = pk;
            }
        }
        // Pb rows of this wave written & read by the same wave -> no barrier

        // ---- PV: O += P @ V (both in permuted-key pos order) ----
        bf16x8 pf[2][2];
#pragma unroll
        for (int i = 0; i < 2; i++)
#pragma unroll
            for (int c = 0; c < 2; c++)
                pf[i][c] = ldsv8(&Pb[(wm + i * 16 + lr) * 64 + (c ? ch1 : ch0) * 8]);
#pragma unroll
        for (int j = 0; j < 4; j++) {
            bf16x8 vf0 = ldsv8(&Vt[(j * 16 + lr) * 64 + ch0 * 8]);
            bf16x8 vf1 = ldsv8(&Vt[(j * 16 + lr) * 64 + ch1 * 8]);
            oac[0][j] = __builtin_amdgcn_mfma_f32_16x16x32_bf16(pf[0][0], vf0, oac[0][j], 0, 0, 0);
            oac[0][j] = __builtin_amdgcn_mfma_f32_16x16x32_bf16(pf[0][1], vf1, oac[0][j], 0, 0, 0);
            oac[1][j] = __builtin_amdgcn_mfma_f32_16x16x32_bf16(pf[1][0], vf0, oac[1][j], 0, 0, 0);
            oac[1][j] = __builtin_amdgcn_mfma_f32_16x16x32_bf16(pf[1][1], vf1, oac[1][j], 0, 0, 0);
        }
    }

    // ---- epilogue: reduce l across the row's 16 lanes, divide, store ----
#pragma unroll
    for (int i = 0; i < 2; i++)
#pragma unroll
        for (int rr = 0; rr < 4; rr++) {
            float l = lsum[i][rr];
            l += __shfl_xor(l, 1);
            l += __shfl_xor(l, 2);
            l += __shfl_xor(l, 4);
            l += __shfl_xor(l, 8);
            const float inv = 1.0f / l;
            const int row = q0 + wm + i * 16 + quad * 4 + rr;
            unsigned short* op = O + (size_t)(b * 1024 + row) * 1024 + h * 64;
#pragma unroll
            for (int j = 0; j < 4; j++)
                op[j * 16 + lr] = f2bf1(oac[i][j][rr] * inv);
        }
}

// ------------- fused partial-sum + bias + residual-add + LayerNorm --------------
#define PSTRIDE ((size_t)4096 * 1024)
__global__ __launch_bounds__(256) void add_ln_kernel(
    const float* __restrict__ P, int nparts, const float* __restrict__ lbias,
    const float* __restrict__ R,
    const float* __restrict__ g, const float* __restrict__ bb,
    float* __restrict__ outF, unsigned short* __restrict__ outB)
{
    const int row = blockIdx.x, tid = threadIdx.x;
    float4v z = ((const float4v*)(R + (size_t)row * 1024))[tid];
    for (int p = 0; p < nparts; ++p)
        z += ((const float4v*)(P + p * PSTRIDE + (size_t)row * 1024))[tid];
    if (lbias) z += ((const float4v*)lbias)[tid];
    float s = z.x + z.y + z.z + z.w;
    float sq = z.x * z.x + z.y * z.y + z.z * z.z + z.w * z.w;
#pragma unroll
    for (int off = 32; off > 0; off >>= 1) {
        s += __shfl_down(s, off);
        sq += __shfl_down(sq, off);
    }
    __shared__ float ws[4], wsq[4];
    __shared__ float sm, sr;
    if ((tid & 63) == 0) { ws[tid >> 6] = s; wsq[tid >> 6] = sq; }
    __syncthreads();
    if (tid == 0) {
        float S1 = ws[0] + ws[1] + ws[2] + ws[3];
        float S2 = wsq[0] + wsq[1] + wsq[2] + wsq[3];
        float mean = S1 * (1.0f / 1024.0f);
        float var = S2 * (1.0f / 1024.0f) - mean * mean;
        sm = mean;
        sr = rsqrtf(var + 1e-5f);
    }
    __syncthreads();
    const float mean = sm, rstd = sr;
    const float4v* g4 = (const float4v*)g;
    const float4v* b4 = (const float4v*)bb;
    float4v res = g4[tid] * ((z - mean) * rstd) + b4[tid];
    if (outF) ((float4v*)(outF + (size_t)row * 1024))[tid] = res;
    if (outB) {
        uint2v u = { f2bf2(res.x, res.y), f2bf2(res.z, res.w) };
        *(uint2v*)(outB + (size_t)row * 1024 + tid * 4) = u;
    }
}

// ---------------- transpose + convert: S[R][C] f32 -> D[C][R] bf16 --------------
__device__ __forceinline__ void tconv_body(const float* __restrict__ S,
                                           unsigned short* __restrict__ D,
                                           int R, int C, int r0, int c0)
{
    __shared__ float tile[64][65];
    const int tid = threadIdx.x;
    const int tr = tid >> 4, tc4 = (tid & 15) * 4;
#pragma unroll
    for (int i = 0; i < 4; i++) {
        const int rr = i * 16 + tr;
        *(float4v*)&tile[rr][tc4] = *(const float4v*)(S + (size_t)(r0 + rr) * C + c0 + tc4);
    }
    __syncthreads();
#pragma unroll
    for (int i = 0; i < 4; i++) {
        const int dr = i * 16 + tr;   // dst row = src col
        float v0 = tile[tc4 + 0][dr];
        float v1 = tile[tc4 + 1][dr];
        float v2 = tile[tc4 + 2][dr];
        float v3 = tile[tc4 + 3][dr];
        uint2v u = { f2bf2(v0, v1), f2bf2(v2, v3) };
        *(uint2v*)(D + (size_t)(c0 + dr) * R + r0 + tc4) = u;
    }
}
__global__ __launch_bounds__(256) void transpose_conv(
    const float* __restrict__ S, unsigned short* __restrict__ D, int R, int C)
{
    tconv_body(S, D, R, C, blockIdx.y * 64, blockIdx.x * 64);
}
__global__ __launch_bounds__(256) void transpose8(
    const float* s0, const float* s1, const float* s2, const float* s3,
    const float* s4, const float* s5, const float* s6, const float* s7,
    unsigned short* d0, unsigned short* d1, unsigned short* d2, unsigned short* d3,
    unsigned short* d4, unsigned short* d5, unsigned short* d6, unsigned short* d7)
{
    const float* S;
    unsigned short* D;
    switch (blockIdx.z) {
        case 0: S = s0; D = d0; break;
        case 1: S = s1; D = d1; break;
        case 2: S = s2; D = d2; break;
        case 3: S = s3; D = d3; break;
        case 4: S = s4; D = d4; break;
        case 5: S = s5; D = d5; break;
        case 6: S = s6; D = d6; break;
        default: S = s7; D = d7; break;
    }
    tconv_body(S, D, 1024, 1024, blockIdx.y * 64, blockIdx.x * 64);
}

// ---------------- f32 -> bf16 convert (two buffers of 4M elems) -----------------
__global__ __launch_bounds__(256) void convert_bf16(
    const float* __restrict__ s0, unsigned short* __restrict__ d0,
    const float* __restrict__ s1, unsigned short* __restrict__ d1)
{
    const float* s = blockIdx.y ? s1 : s0;
    unsigned short* d = blockIdx.y ? d1 : d0;
    const size_t i = ((size_t)blockIdx.x * 256 + threadIdx.x) * 4;
    float4v v = *(const float4v*)(s + i);
    uint2v u = { f2bf2(v.x, v.y), f2bf2(v.z, v.w) };
    *(uint2v*)(d + i) = u;
}

// ------------- concat biases + int->float mask conversion -----------------------
__global__ __launch_bounds__(256) void biascat(
    const float* __restrict__ sbq, const float* __restrict__ sbk, const float* __restrict__ sbv,
    const float* __restrict__ cbk, const float* __restrict__ cbv,
    const int* __restrict__ smask, const int* __restrict__ cmask,
    float* __restrict__ bq, float* __restrict__ bc,
    float* __restrict__ smf, float* __restrict__ cmf)
{
    const int i = blockIdx.x * 256 + threadIdx.x;
    if (i < 3072)
        bq[i] = i < 1024 ? sbq[i] : (i < 2048 ? sbk[i - 1024] : sbv[i - 2048]);
    else if (i < 5120) {
        const int j = i - 3072;
        bc[j] = j < 1024 ? cbk[j] : cbv[j - 1024];
    } else if (i < 9216)
        smf[i - 5120] = (float)smask[i - 5120];
    else
        cmf[i - 9216] = (float)cmask[i - 9216];
}

// --------------------------------------------------------------------------------
extern "C" void kernel_launch(void* const* d_in, const int* in_sizes, int n_in,
                              void* d_out, int out_size, void* d_ws, size_t ws_size,
                              hipStream_t stream)
{
    const float* x     = (const float*)d_in[0];
    const int*   smask = (const int*)d_in[1];
    const float* cx    = (const float*)d_in[2];
    const int*   cmask = (const int*)d_in[3];
    const float* sWq = (const float*)d_in[5],  *sbq = (const float*)d_in[6];
    const float* sWk = (const float*)d_in[7],  *sbk = (const float*)d_in[8];
    const float* sWv = (const float*)d_in[9],  *sbv = (const float*)d_in[10];
    const float* sWo = (const float*)d_in[11], *sbo = (const float*)d_in[12];
    const float* cWq = (const float*)d_in[13], *cbq = (const float*)d_in[14];
    const float* cWk = (const float*)d_in[15], *cbk = (const float*)d_in[16];
    const float* cWv = (const float*)d_in[17], *cbv = (const float*)d_in[18];
    const float* cWo = (const float*)d_in[19], *cbo = (const float*)d_in[20];
    const float* g   = (const float*)d_in[21], *bb  = (const float*)d_in[22];
    const float* W1  = (const float*)d_in[23], *b1  = (const float*)d_in[24];
    const float* W2  = (const float*)d_in[25], *b2  = (const float*)d_in[26];
    float* out = (float*)d_out;

    const size_t MB = 1024 * 1024;
    unsigned char* ws = (unsigned char*)d_ws;
    // phase-overlapped layout (see liveness notes):
    unsigned short* xb   = (unsigned short*)(ws + 0 * MB);    // 8 MB
    unsigned short* cxb  = (unsigned short*)(ws + 8 * MB);    // 8 MB
    unsigned short* SANb = (unsigned short*)(ws + 16 * MB);   // 8 MB
    unsigned short* CQ   = (unsigned short*)(ws + 24 * MB);   // 8 MB
    unsigned short* MID  = (unsigned short*)(ws + 0 * MB);    // 32 MB (FFN; xb..CQ dead)
    unsigned short* QK   = (unsigned short*)(ws + 32 * MB);   // 16 MB [4096][2048]
    unsigned short* VTs  = (unsigned short*)(ws + 48 * MB);   // 8 MB [(b,h,d)][1024]
    float*          P    = (float*)(ws + 32 * MB);            // 2x16 MB (QK/VTs/CKb dead)
    unsigned short* CKb  = (unsigned short*)(ws + 56 * MB);   // 8 MB [4096][1024]
    unsigned short* VTc  = (unsigned short*)(ws + 64 * MB);   // 8 MB
    unsigned short* T    = (unsigned short*)(ws + 72 * MB);   // 8 MB
    float*          HH   = (float*)(ws + 80 * MB);            // 16 MB
    unsigned short* HHb  = (unsigned short*)(ws + 96 * MB);   // 8 MB
    unsigned short* WtQKV = (unsigned short*)(ws + 104 * MB); // 6 MB [3072][1024]
    unsigned short* WtCKV = (unsigned short*)(ws + 110 * MB); // 4 MB [2048][1024]
    unsigned short* WtSWO = (unsigned short*)(ws + 114 * MB); // 2 MB
    unsigned short* WtCWQ = (unsigned short*)(ws + 116 * MB); // 2 MB
    unsigned short* WtCWO = (unsigned short*)(ws + 118 * MB); // 2 MB
    unsigned short* WtW1  = (unsigned short*)(ws + 120 * MB); // 8 MB
    unsigned short* WtW2  = (unsigned short*)(ws + 128 * MB); // 8 MB
    float* biasQ = (float*)(ws + 136 * MB);                   // 12 KB
    float* biasC = (float*)(ws + 136 * MB + 16 * 1024);       // 8 KB
    float* smf   = (float*)(ws + 136 * MB + 32 * 1024);       // 16 KB
    float* cmf   = (float*)(ws + 136 * MB + 48 * 1024);       // 16 KB

    dim3 blk(256);

    // ---- conversions (once per call) ----
    convert_bf16<<<dim3(4096, 2), blk, 0, stream>>>(x, xb, cx, cxb);
    transpose8<<<dim3(16, 16, 8), blk, 0, stream>>>(
        sWq, sWk, sWv, cWk, cWv, sWo, cWq, cWo,
        WtQKV, WtQKV + 1024 * 1024, WtQKV + 2 * 1024 * 1024,
        WtCKV, WtCKV + 1024 * 1024,
        WtSWO, WtCWQ, WtCWO);
    transpose_conv<<<dim3(64, 16), blk, 0, stream>>>(W1, WtW1, 1024, 4096);
    transpose_conv<<<dim3(16, 64), blk, 0, stream>>>(W2, WtW2, 4096, 1024);
    biascat<<<52, blk, 0, stream>>>(sbq, sbk, sbv, cbk, cbv, smask, cmask,
                                    biasQ, biasC, smf, cmf);

    // ---- self attention ----
    gemm_bt<0, 1, 0, 1><<<dim3(32, 24), blk, 0, stream>>>(
        xb, WtQKV, biasQ, QK, 4096, 3072, 1024, 2048, 1024, 2048, VTs);
    attn_mfma<<<dim3(8, 16, 4), blk, 0, stream>>>(QK, 2048, QK + 1024, 2048, VTs, smf, T);
    gemm_bt<0, 0, 1, 1><<<dim3(32, 8, 2), blk, 0, stream>>>(
        T, WtSWO, nullptr, P, 4096, 1024, 1024, 1024, 0, VBIG, nullptr);
    add_ln_kernel<<<4096, blk, 0, stream>>>(P, 2, sbo, x, g, bb, nullptr, SANb);

    // ---- cross attention (residual = ORIGINAL x) ----
    gemm_bt<0, 1, 1, 1><<<dim3(32, 8), blk, 0, stream>>>(
        SANb, WtCWQ, cbq, CQ, 4096, 1024, 1024, 1024, 1024, VBIG, nullptr);
    gemm_bt<0, 1, 1, 1><<<dim3(32, 16), blk, 0, stream>>>(
        cxb, WtCKV, biasC, CKb, 4096, 2048, 1024, 1024, 0, 1024, VTc);
    attn_mfma<<<dim3(8, 16, 4), blk, 0, stream>>>(CQ, 1024, CKb, 1024, VTc, cmf, T);
    gemm_bt<0, 0, 1, 1><<<dim3(32, 8, 2), blk, 0, stream>>>(
        T, WtCWO, nullptr, P, 4096, 1024, 1024, 1024, 0, VBIG, nullptr);
    add_ln_kernel<<<4096, blk, 0, stream>>>(P, 2, cbo, x, g, bb, HH, HHb);

    // ---- FFN ----
    gemm_bt<1, 1, 0, 0><<<dim3(32, 32), blk, 0, stream>>>(
        HHb, WtW1, b1, MID, 4096, 4096, 1024, 4096, 0, VBIG, nullptr);
    gemm_bt<0, 0, 1, 1><<<dim3(32, 8, 2), blk, 0, stream>>>(
        MID, WtW2, nullptr, P, 4096, 1024, 4096, 1024, 0, VBIG, nullptr);
    add_ln_kernel<<<4096, blk, 0, stream>>>(P, 2, b2, HH, g, bb, out, nullptr);
}

// Round 7
// 475.201 us; speedup vs baseline: 3.3785x; 1.0316x over previous
//
#include <hip/hip_runtime.h>
#include <hip/hip_bf16.h>

// Decoder block: self-MHA -> add+LN -> cross-MHA -> add+LN(resid=orig x) -> FFN -> add+LN
// B=4 S=1024 H=1024 NH=16 d=64.
// bf16 MFMA GEMMs, global_load_lds(16B) + XOR-swizzled LDS; split-K=2 (bf16
// partials) + LN-fused reduction for O-proj/FFN2. Attention: no-max flash,
// V^T pre-transposed+pos-permuted by producer GEMM epilogues.
// R7: one fused prep kernel; CQ+CKV fused into one launch (3 blocks/CU).

typedef float float4v __attribute__((ext_vector_type(4)));
typedef __bf16 bf16x8 __attribute__((ext_vector_type(8)));
typedef unsigned short ushort8 __attribute__((ext_vector_type(8)));
typedef unsigned int uint2v __attribute__((ext_vector_type(2)));

#define VBIG (1 << 29)

__device__ __forceinline__ unsigned short f2bf1(float f) {
    unsigned u = __builtin_bit_cast(unsigned, f);
    u += 0x7fffu + ((u >> 16) & 1u);
    return (unsigned short)(u >> 16);
}
__device__ __forceinline__ unsigned f2bf2(float lo, float hi) {
    unsigned a = __builtin_bit_cast(unsigned, lo);
    a += 0x7fffu + ((a >> 16) & 1u);
    unsigned b = __builtin_bit_cast(unsigned, hi);
    b += 0x7fffu + ((b >> 16) & 1u);
    return (a >> 16) | (b & 0xffff0000u);
}
__device__ __forceinline__ float4v bf4_to_f4(uint2v u) {
    float4v r;
    r.x = __builtin_bit_cast(float, (u.x & 0xffffu) << 16);
    r.y = __builtin_bit_cast(float, u.x & 0xffff0000u);
    r.z = __builtin_bit_cast(float, (u.y & 0xffffu) << 16);
    r.w = __builtin_bit_cast(float, u.y & 0xffff0000u);
    return r;
}
__device__ __forceinline__ bf16x8 ldsv8(const unsigned short* p) {
    return __builtin_bit_cast(bf16x8, *(const ushort8*)p);
}
// async global->LDS, 16B per lane; LDS dest = wave-uniform base + lane*16
__device__ __forceinline__ void async16(const unsigned short* g, unsigned short* l) {
    __builtin_amdgcn_global_load_lds(
        (const __attribute__((address_space(1))) unsigned int*)(g),
        (__attribute__((address_space(3))) unsigned int*)(l),
        16, 0, 0);
}

// ---------------- GEMM core: C[M,N] = A[M,K] @ Bt[N,K]^T (+ bias) --------------
// 128x128 tile, BK=64, 4 waves 2x2 of 64x64, 16x16x32 MFMA. bf16 output always.
// vrel >= 0: V^T pos-permuted epilogue into VTout (token t -> (t&~63)+pos(t&63),
// pos(k)=(k&15)*4+(k>>4)); vrel = col offset rel. to V region start.
template <int RELU, int DBUF>
__device__ __forceinline__ void gemm_core(
    const unsigned short* __restrict__ A, const unsigned short* __restrict__ Bt,
    const float* __restrict__ bias, unsigned short* __restrict__ Cout,
    int m0, int n0, int K, int KL, int kbase, int ldc,
    float qs, int vrel, unsigned short* __restrict__ VTout, size_t outoff)
{
    __shared__ __align__(16) unsigned short As[(DBUF ? 2 : 1) * 128 * 64];
    __shared__ __align__(16) unsigned short Bs[(DBUF ? 2 : 1) * 128 * 64];

    const int tid = threadIdx.x;
    const int w = tid >> 6, lane = tid & 63;
    const int lr = lane & 15, quad = lane >> 4;
    const int wm = (w >> 1) * 64, wn = (w & 1) * 64;

    const int sr = lane >> 3, sc = lane & 7;
    const int fch = sc ^ sr;                       // swizzled source chunk
    const unsigned short* Ag = A + (size_t)(m0 + w * 32 + sr) * K + kbase + fch * 8;
    const unsigned short* Bg = Bt + (size_t)(n0 + w * 32 + sr) * K + kbase + fch * 8;

    float4v acc[4][4];
#pragma unroll
    for (int i = 0; i < 4; i++)
#pragma unroll
        for (int j = 0; j < 4; j++) acc[i][j] = 0.f;

    const int ch0 = quad ^ (lr & 7);
    const int ch1 = (4 + quad) ^ (lr & 7);

    auto issue = [&](int buf, int k0) {
        unsigned short* Al = &As[buf * (128 * 64) + (w * 32) * 64];
        unsigned short* Bl = &Bs[buf * (128 * 64) + (w * 32) * 64];
#pragma unroll
        for (int i = 0; i < 4; i++) {
            async16(Ag + (size_t)(i * 8) * K + k0, Al + (i * 8) * 64);
            async16(Bg + (size_t)(i * 8) * K + k0, Bl + (i * 8) * 64);
        }
    };
    auto compute = [&](int buf) {
        const unsigned short* Ab = &As[buf * (128 * 64)];
        const unsigned short* Bb = &Bs[buf * (128 * 64)];
#pragma unroll
        for (int kk = 0; kk < 2; kk++) {
            const int ch = kk ? ch1 : ch0;
            bf16x8 af[4], bf[4];
#pragma unroll
            for (int i = 0; i < 4; i++) {
                af[i] = ldsv8(&Ab[(wm + i * 16 + lr) * 64 + ch * 8]);
                bf[i] = ldsv8(&Bb[(wn + i * 16 + lr) * 64 + ch * 8]);
            }
#pragma unroll
            for (int i = 0; i < 4; i++)
#pragma unroll
                for (int j = 0; j < 4; j++)
                    acc[i][j] = __builtin_amdgcn_mfma_f32_16x16x32_bf16(af[i], bf[j], acc[i][j], 0, 0, 0);
        }
    };

    if (DBUF) {
        const int NIT = KL >> 6;
        issue(0, 0);
        for (int it = 0; it < NIT; ++it) {
            const int nxt = it + 1;
            if (nxt < NIT) {
                issue(nxt & 1, nxt << 6);
                __builtin_amdgcn_sched_barrier(0);
                __builtin_amdgcn_s_waitcnt(0x0F78);   // vmcnt(8): iter-it loads done
            } else {
                __builtin_amdgcn_sched_barrier(0);
                __builtin_amdgcn_s_waitcnt(0x0F70);   // vmcnt(0)
            }
            __builtin_amdgcn_s_barrier();
            __builtin_amdgcn_sched_barrier(0);
            compute(it & 1);
            __builtin_amdgcn_sched_barrier(0);
            __builtin_amdgcn_s_barrier();             // readers done before buf reuse
            __builtin_amdgcn_sched_barrier(0);
        }
    } else {
        for (int k0 = 0; k0 < KL; k0 += 64) {
            issue(0, k0);
            __syncthreads();
            compute(0);
            __syncthreads();
        }
    }

    if (vrel >= 0) {
        // ---- V^T pos-permuted epilogue ----
        const int crel = vrel + wn;                   // multiple of 64
        const int hh = crel >> 6;
        const int bidx = (m0 + wm) >> 10;
        const int tbase = ((m0 + wm) & 1023) + quad * 16;
#pragma unroll
        for (int j = 0; j < 4; j++) {
            const float bv = bias ? bias[n0 + wn + j * 16 + lr] : 0.f;
            const int d = j * 16 + lr;
            unsigned short* vp = VTout + ((size_t)(bidx * 16 + hh) * 64 + d) * 1024 + tbase;
#pragma unroll
            for (int r = 0; r < 4; r++) {
                uint2v u = { f2bf2(acc[0][j][r] + bv, acc[1][j][r] + bv),
                             f2bf2(acc[2][j][r] + bv, acc[3][j][r] + bv) };
                *(uint2v*)(vp + r * 4) = u;
            }
        }
        return;
    }

#pragma unroll
    for (int j = 0; j < 4; j++) {
        const int col = n0 + wn + j * 16 + lr;
        const float bv = bias ? bias[col] : 0.f;
#pragma unroll
        for (int i = 0; i < 4; i++) {
            const int row0 = m0 + wm + i * 16 + quad * 4;
#pragma unroll
            for (int r = 0; r < 4; r++) {
                float v = (acc[i][j][r] + bv) * qs;
                if (RELU) v = fmaxf(v, 0.f);
                Cout[outoff + (size_t)(row0 + r) * ldc + col] = f2bf1(v);
            }
        }
    }
}

// Generic GEMM kernel (runtime order, split-K via gridDim.z, qscale cols, V cols)
template <int RELU, int DBUF>
__global__ __launch_bounds__(256) void gemm_bt(
    const unsigned short* __restrict__ A, const unsigned short* __restrict__ Bt,
    const float* __restrict__ bias, unsigned short* __restrict__ Cout,
    int M, int N, int K, int ldc, int order, int qcols, int vcol0,
    unsigned short* __restrict__ VTout)
{
    const int m0 = (order ? blockIdx.x : blockIdx.y) * 128;
    const int n0 = (order ? blockIdx.y : blockIdx.x) * 128;
    const int KL = K / gridDim.z;
    const int kbase = blockIdx.z * KL;
    const float qs = (n0 < qcols) ? 0.015625f : 1.0f;
    const int vrel = (n0 >= vcol0) ? n0 - vcol0 : -1;
    const size_t outoff = (size_t)blockIdx.z * M * ldc;
    gemm_core<RELU, DBUF>(A, Bt, bias, Cout, m0, n0, K, KL, kbase, ldc,
                          qs, vrel, VTout, outoff);
}

// Fused cross-phase GEMM: y<8 -> CQ = SANb@WtCWQ^T (1/64-scaled);
// y in [8,16) -> CK = cxb@WtCKV^T cols [0,1024); y in [16,24) -> V^T epilogue.
__global__ __launch_bounds__(256) void gemm_cross(
    const unsigned short* __restrict__ SANb, const unsigned short* __restrict__ WtCWQ,
    const float* __restrict__ cbq, unsigned short* __restrict__ CQ,
    const unsigned short* __restrict__ cxb, const unsigned short* __restrict__ WtCKV,
    const float* __restrict__ biasC, unsigned short* __restrict__ CKb,
    unsigned short* __restrict__ VTc)
{
    const int m0 = blockIdx.x * 128;
    const int y = blockIdx.y;
    const unsigned short *Ax, *Btx;
    const float* bx;
    unsigned short* Cx = nullptr;
    unsigned short* vt = nullptr;
    int n0, ldc = 1024, vrel = -1;
    float qs = 1.0f;
    if (y < 8) {
        Ax = SANb; Btx = WtCWQ; bx = cbq; Cx = CQ; n0 = y * 128; qs = 0.015625f;
    } else {
        Ax = cxb; Btx = WtCKV; bx = biasC; n0 = (y - 8) * 128;
        if (n0 < 1024) Cx = CKb;
        else { vrel = n0 - 1024; vt = VTc; }
    }
    gemm_core<0, 0>(Ax, Btx, bx, Cx, m0, n0, 1024, 1024, 0, ldc, qs, vrel, vt, 0);
}

// ---------------- MFMA flash attention (bf16 in/out), no-max variant -----------
__global__ __launch_bounds__(256) void attn_mfma(
    const unsigned short* __restrict__ Q, int qs,
    const unsigned short* __restrict__ K, int kvs,
    const unsigned short* __restrict__ VT,     // [(b*16+h)*64+d][1024], pos-permuted
    const float* __restrict__ maskf,           // [b][1024]
    unsigned short* __restrict__ O)
{
    __shared__ __align__(16) unsigned short Ks[64 * 64];   // [key][d]
    __shared__ __align__(16) unsigned short Vt[64 * 64];   // [d][pos]
    __shared__ __align__(16) unsigned short Pb[128 * 64];  // [q][pos]

    const int tid = threadIdx.x;
    const int b = blockIdx.z, h = blockIdx.y, q0 = blockIdx.x * 128;
    const int w = tid >> 6, lane = tid & 63;
    const int lr = lane & 15, quad = lane >> 4;
    const int wm = w * 32;
    const float4v zf = {0.f, 0.f, 0.f, 0.f};

    bf16x8 qf[2][2];
#pragma unroll
    for (int i = 0; i < 2; i++)
#pragma unroll
        for (int c = 0; c < 2; c++)
            qf[i][c] = ldsv8(Q + (size_t)(b * 1024 + q0 + wm + i * 16 + lr) * qs
                             + h * 64 + c * 32 + quad * 8);

    const int sr = lane >> 3, sc = lane & 7;
    const int fch = sc ^ sr;
    const int ch0 = quad ^ (lr & 7), ch1 = (4 + quad) ^ (lr & 7);
    const unsigned short* VTb = VT + (size_t)(b * 16 + h) * 64 * 1024;

    float4v oac[2][4];
    float lsum[2][4];
#pragma unroll
    for (int i = 0; i < 2; i++) {
#pragma unroll
        for (int j = 0; j < 4; j++) oac[i][j] = zf;
#pragma unroll
        for (int rr = 0; rr < 4; rr++) lsum[i][rr] = 0.f;
    }

    for (int kb = 0; kb < 16; ++kb) {
        const int s0 = kb * 64;
        __syncthreads();   // prev iter's Ks/Vt reads done
#pragma unroll
        for (int i = 0; i < 2; i++) {
            async16(K + (size_t)(b * 1024 + s0 + w * 16 + i * 8 + sr) * kvs + h * 64 + fch * 8,
                    &Ks[(w * 16 + i * 8) * 64]);
            async16(VTb + (size_t)(w * 16 + i * 8 + sr) * 1024 + s0 + fch * 8,
                    &Vt[(w * 16 + i * 8) * 64]);
        }
        float mf[4];
#pragma unroll
        for (int j = 0; j < 4; j++)
            mf[j] = maskf[b * 1024 + s0 + j * 16 + lr];
        __syncthreads();

        // ---- QK^T: 32 q-rows x 64 keys per wave ----
        float4v sa[2][4];
#pragma unroll
        for (int j = 0; j < 4; j++) {
            const int krow = j * 16 + lr;
            bf16x8 kf0 = ldsv8(&Ks[krow * 64 + ch0 * 8]);
            bf16x8 kf1 = ldsv8(&Ks[krow * 64 + ch1 * 8]);
            sa[0][j] = __builtin_amdgcn_mfma_f32_16x16x32_bf16(qf[0][0], kf0, zf, 0, 0, 0);
            sa[0][j] = __builtin_amdgcn_mfma_f32_16x16x32_bf16(qf[0][1], kf1, sa[0][j], 0, 0, 0);
            sa[1][j] = __builtin_amdgcn_mfma_f32_16x16x32_bf16(qf[1][0], kf0, zf, 0, 0, 0);
            sa[1][j] = __builtin_amdgcn_mfma_f32_16x16x32_bf16(qf[1][1], kf1, sa[1][j], 0, 0, 0);
        }

        // ---- p = exp(s) * mask; lane-local l partials; packed b64 P stores ----
#pragma unroll
        for (int i = 0; i < 2; i++) {
#pragma unroll
            for (int rr = 0; rr < 4; rr++) {
                const float p0 = __expf(sa[i][0][rr]) * mf[0];
                const float p1 = __expf(sa[i][1][rr]) * mf[1];
                const float p2 = __expf(sa[i][2][rr]) * mf[2];
                const float p3 = __expf(sa[i][3][rr]) * mf[3];
                lsum[i][rr] += (p0 + p1) + (p2 + p3);
                const int row = wm + i * 16 + quad * 4 + rr;
                const int schp = (lr >> 1) ^ (row & 7);
                uint2v pk = { f2bf2(p0, p1), f2bf2(p2, p3) };
                *(uint2v*)&Pb[row * 64 + schp * 8 + (lr & 1) * 4] = pk;
            }
        }
        // Pb rows of this wave written & read by the same wave -> no barrier

        // ---- PV: O += P @ V (both in permuted-key pos order) ----
        bf16x8 pf[2][2];
#pragma unroll
        for (int i = 0; i < 2; i++)
#pragma unroll
            for (int c = 0; c < 2; c++)
                pf[i][c] = ldsv8(&Pb[(wm + i * 16 + lr) * 64 + (c ? ch1 : ch0) * 8]);
#pragma unroll
        for (int j = 0; j < 4; j++) {
            bf16x8 vf0 = ldsv8(&Vt[(j * 16 + lr) * 64 + ch0 * 8]);
            bf16x8 vf1 = ldsv8(&Vt[(j * 16 + lr) * 64 + ch1 * 8]);
            oac[0][j] = __builtin_amdgcn_mfma_f32_16x16x32_bf16(pf[0][0], vf0, oac[0][j], 0, 0, 0);
            oac[0][j] = __builtin_amdgcn_mfma_f32_16x16x32_bf16(pf[0][1], vf1, oac[0][j], 0, 0, 0);
            oac[1][j] = __builtin_amdgcn_mfma_f32_16x16x32_bf16(pf[1][0], vf0, oac[1][j], 0, 0, 0);
            oac[1][j] = __builtin_amdgcn_mfma_f32_16x16x32_bf16(pf[1][1], vf1, oac[1][j], 0, 0, 0);
        }
    }

    // ---- epilogue: reduce l across the row's 16 lanes, divide, store ----
#pragma unroll
    for (int i = 0; i < 2; i++)
#pragma unroll
        for (int rr = 0; rr < 4; rr++) {
            float l = lsum[i][rr];
            l += __shfl_xor(l, 1);
            l += __shfl_xor(l, 2);
            l += __shfl_xor(l, 4);
            l += __shfl_xor(l, 8);
            const float inv = 1.0f / l;
            const int row = q0 + wm + i * 16 + quad * 4 + rr;
            unsigned short* op = O + (size_t)(b * 1024 + row) * 1024 + h * 64;
#pragma unroll
            for (int j = 0; j < 4; j++)
                op[j * 16 + lr] = f2bf1(oac[i][j][rr] * inv);
        }
}

// ------------- fused partial-sum(bf16) + bias + residual-add + LayerNorm --------
#define PSTRIDE ((size_t)4096 * 1024)
__global__ __launch_bounds__(256) void add_ln_kernel(
    const unsigned short* __restrict__ P, int nparts, const float* __restrict__ lbias,
    const float* __restrict__ R,
    const float* __restrict__ g, const float* __restrict__ bb,
    float* __restrict__ outF, unsigned short* __restrict__ outB)
{
    const int row = blockIdx.x, tid = threadIdx.x;
    float4v z = ((const float4v*)(R + (size_t)row * 1024))[tid];
    for (int p = 0; p < nparts; ++p)
        z += bf4_to_f4(*(const uint2v*)(P + p * PSTRIDE + (size_t)row * 1024 + tid * 4));
    if (lbias) z += ((const float4v*)lbias)[tid];
    float s = z.x + z.y + z.z + z.w;
    float sq = z.x * z.x + z.y * z.y + z.z * z.z + z.w * z.w;
#pragma unroll
    for (int off = 32; off > 0; off >>= 1) {
        s += __shfl_down(s, off);
        sq += __shfl_down(sq, off);
    }
    __shared__ float ws[4], wsq[4];
    __shared__ float sm, sr;
    if ((tid & 63) == 0) { ws[tid >> 6] = s; wsq[tid >> 6] = sq; }
    __syncthreads();
    if (tid == 0) {
        float S1 = ws[0] + ws[1] + ws[2] + ws[3];
        float S2 = wsq[0] + wsq[1] + wsq[2] + wsq[3];
        float mean = S1 * (1.0f / 1024.0f);
        float var = S2 * (1.0f / 1024.0f) - mean * mean;
        sm = mean;
        sr = rsqrtf(var + 1e-5f);
    }
    __syncthreads();
    const float mean = sm, rstd = sr;
    const float4v* g4 = (const float4v*)g;
    const float4v* b4 = (const float4v*)bb;
    float4v res = g4[tid] * ((z - mean) * rstd) + b4[tid];
    if (outF) ((float4v*)(outF + (size_t)row * 1024))[tid] = res;
    if (outB) {
        uint2v u = { f2bf2(res.x, res.y), f2bf2(res.z, res.w) };
        *(uint2v*)(outB + (size_t)row * 1024 + tid * 4) = u;
    }
}

// ---------------- transpose + convert body: S[R][C] f32 -> D[C][R] bf16 ---------
__device__ __forceinline__ void tconv_body(const float* __restrict__ S,
                                           unsigned short* __restrict__ D,
                                           int R, int C, int r0, int c0)
{
    __shared__ float tile[64][65];
    const int tid = threadIdx.x;
    const int tr = tid >> 4, tc4 = (tid & 15) * 4;
#pragma unroll
    for (int i = 0; i < 4; i++) {
        const int rr = i * 16 + tr;
        *(float4v*)&tile[rr][tc4] = *(const float4v*)(S + (size_t)(r0 + rr) * C + c0 + tc4);
    }
    __syncthreads();
#pragma unroll
    for (int i = 0; i < 4; i++) {
        const int dr = i * 16 + tr;   // dst row = src col
        float v0 = tile[tc4 + 0][dr];
        float v1 = tile[tc4 + 1][dr];
        float v2 = tile[tc4 + 2][dr];
        float v3 = tile[tc4 + 3][dr];
        uint2v u = { f2bf2(v0, v1), f2bf2(v2, v3) };
        *(uint2v*)(D + (size_t)(c0 + dr) * R + r0 + tc4) = u;
    }
}

// ---------------- single fused prep kernel --------------------------------------
// blocks [0,8192): x/cx f32->bf16; [8192,10240): 8 square 1024^2 transposes;
// [10240,11264): W1^T; [11264,12288): W2^T; [12288,12340): biases+masks.
__global__ __launch_bounds__(256) void prep_all(
    const float* __restrict__ x, const float* __restrict__ cx,
    unsigned short* __restrict__ xb, unsigned short* __restrict__ cxb,
    const float* s0, const float* s1, const float* s2, const float* s3,
    const float* s4, const float* s5, const float* s6, const float* s7,
    unsigned short* d0, unsigned short* d1, unsigned short* d2, unsigned short* d3,
    unsigned short* d4, unsigned short* d5, unsigned short* d6, unsigned short* d7,
    const float* __restrict__ W1, unsigned short* __restrict__ WtW1,
    const float* __restrict__ W2, unsigned short* __restrict__ WtW2,
    const float* __restrict__ sbq, const float* __restrict__ sbk, const float* __restrict__ sbv,
    const float* __restrict__ cbk, const float* __restrict__ cbv,
    const int* __restrict__ smask, const int* __restrict__ cmask,
    float* __restrict__ bq, float* __restrict__ bc,
    float* __restrict__ smf, float* __restrict__ cmf)
{
    const int bid = blockIdx.x, tid = threadIdx.x;
    if (bid < 8192) {
        const float* s = bid < 4096 ? x : cx;
        unsigned short* d = bid < 4096 ? xb : cxb;
        const size_t i = ((size_t)(bid & 4095) * 256 + tid) * 4;
        float4v v = *(const float4v*)(s + i);
        uint2v u = { f2bf2(v.x, v.y), f2bf2(v.z, v.w) };
        *(uint2v*)(d + i) = u;
    } else if (bid < 10240) {
        const int t = bid - 8192;
        const int which = t >> 8, sub = t & 255;
        const float* S;
        unsigned short* D;
        switch (which) {
            case 0: S = s0; D = d0; break;
            case 1: S = s1; D = d1; break;
            case 2: S = s2; D = d2; break;
            case 3: S = s3; D = d3; break;
            case 4: S = s4; D = d4; break;
            case 5: S = s5; D = d5; break;
            case 6: S = s6; D = d6; break;
            default: S = s7; D = d7; break;
        }
        tconv_body(S, D, 1024, 1024, (sub >> 4) * 64, (sub & 15) * 64);
    } else if (bid < 11264) {
        const int t = bid - 10240;           // W1: R=1024, C=4096
        tconv_body(W1, WtW1, 1024, 4096, (t >> 6) * 64, (t & 63) * 64);
    } else if (bid < 12288) {
        const int t = bid - 11264;           // W2: R=4096, C=1024
        tconv_body(W2, WtW2, 4096, 1024, (t & 63) * 64, (t >> 6) * 64);
    } else {
        const int i = (bid - 12288) * 256 + tid;
        if (i < 3072)
            bq[i] = i < 1024 ? sbq[i] : (i < 2048 ? sbk[i - 1024] : sbv[i - 2048]);
        else if (i < 5120) {
            const int j = i - 3072;
            bc[j] = j < 1024 ? cbk[j] : cbv[j - 1024];
        } else if (i < 9216)
            smf[i - 5120] = (float)smask[i - 5120];
        else
            cmf[i - 9216] = (float)cmask[i - 9216];
    }
}

// --------------------------------------------------------------------------------
extern "C" void kernel_launch(void* const* d_in, const int* in_sizes, int n_in,
                              void* d_out, int out_size, void* d_ws, size_t ws_size,
                              hipStream_t stream)
{
    const float* x     = (const float*)d_in[0];
    const int*   smask = (const int*)d_in[1];
    const float* cx    = (const float*)d_in[2];
    const int*   cmask = (const int*)d_in[3];
    const float* sWq = (const float*)d_in[5],  *sbq = (const float*)d_in[6];
    const float* sWk = (const float*)d_in[7],  *sbk = (const float*)d_in[8];
    const float* sWv = (const float*)d_in[9],  *sbv = (const float*)d_in[10];
    const float* sWo = (const float*)d_in[11], *sbo = (const float*)d_in[12];
    const float* cWq = (const float*)d_in[13], *cbq = (const float*)d_in[14];
    const float* cWk = (const float*)d_in[15], *cbk = (const float*)d_in[16];
    const float* cWv = (const float*)d_in[17], *cbv = (const float*)d_in[18];
    const float* cWo = (const float*)d_in[19], *cbo = (const float*)d_in[20];
    const float* g   = (const float*)d_in[21], *bb  = (const float*)d_in[22];
    const float* W1  = (const float*)d_in[23], *b1  = (const float*)d_in[24];
    const float* W2  = (const float*)d_in[25], *b2  = (const float*)d_in[26];
    float* out = (float*)d_out;

    const size_t MB = 1024 * 1024;
    unsigned char* ws = (unsigned char*)d_ws;
    unsigned short* xb   = (unsigned short*)(ws + 0 * MB);    // 8 MB
    unsigned short* cxb  = (unsigned short*)(ws + 8 * MB);    // 8 MB
    unsigned short* SANb = (unsigned short*)(ws + 16 * MB);   // 8 MB
    unsigned short* CQ   = (unsigned short*)(ws + 24 * MB);   // 8 MB
    unsigned short* MID  = (unsigned short*)(ws + 0 * MB);    // 32 MB (FFN; xb..CQ dead)
    unsigned short* QK   = (unsigned short*)(ws + 32 * MB);   // 16 MB [4096][2048]
    unsigned short* VTs  = (unsigned short*)(ws + 48 * MB);   // 8 MB [(b,h,d)][1024]
    unsigned short* P    = (unsigned short*)(ws + 32 * MB);   // 2x8 MB bf16 partials
    unsigned short* CKb  = (unsigned short*)(ws + 56 * MB);   // 8 MB [4096][1024]
    unsigned short* VTc  = (unsigned short*)(ws + 64 * MB);   // 8 MB
    unsigned short* T    = (unsigned short*)(ws + 72 * MB);   // 8 MB
    float*          HH   = (float*)(ws + 80 * MB);            // 16 MB
    unsigned short* HHb  = (unsigned short*)(ws + 96 * MB);   // 8 MB
    unsigned short* WtQKV = (unsigned short*)(ws + 104 * MB); // 6 MB [3072][1024]
    unsigned short* WtCKV = (unsigned short*)(ws + 110 * MB); // 4 MB [2048][1024]
    unsigned short* WtSWO = (unsigned short*)(ws + 114 * MB); // 2 MB
    unsigned short* WtCWQ = (unsigned short*)(ws + 116 * MB); // 2 MB
    unsigned short* WtCWO = (unsigned short*)(ws + 118 * MB); // 2 MB
    unsigned short* WtW1  = (unsigned short*)(ws + 120 * MB); // 8 MB
    unsigned short* WtW2  = (unsigned short*)(ws + 128 * MB); // 8 MB
    float* biasQ = (float*)(ws + 136 * MB);                   // 12 KB
    float* biasC = (float*)(ws + 136 * MB + 16 * 1024);       // 8 KB
    float* smf   = (float*)(ws + 136 * MB + 32 * 1024);       // 16 KB
    float* cmf   = (float*)(ws + 136 * MB + 48 * 1024);       // 16 KB

    dim3 blk(256);

    // ---- all prep in one launch ----
    prep_all<<<12340, blk, 0, stream>>>(
        x, cx, xb, cxb,
        sWq, sWk, sWv, cWk, cWv, sWo, cWq, cWo,
        WtQKV, WtQKV + 1024 * 1024, WtQKV + 2 * 1024 * 1024,
        WtCKV, WtCKV + 1024 * 1024,
        WtSWO, WtCWQ, WtCWO,
        W1, WtW1, W2, WtW2,
        sbq, sbk, sbv, cbk, cbv, smask, cmask, biasQ, biasC, smf, cmf);

    // ---- self attention ----
    gemm_bt<0, 0><<<dim3(32, 24), blk, 0, stream>>>(
        xb, WtQKV, biasQ, QK, 4096, 3072, 1024, 2048, 1, 1024, 2048, VTs);
    attn_mfma<<<dim3(8, 16, 4), blk, 0, stream>>>(QK, 2048, QK + 1024, 2048, VTs, smf, T);
    gemm_bt<0, 1><<<dim3(32, 8, 2), blk, 0, stream>>>(
        T, WtSWO, nullptr, P, 4096, 1024, 1024, 1024, 1, 0, VBIG, nullptr);
    add_ln_kernel<<<4096, blk, 0, stream>>>(P, 2, sbo, x, g, bb, nullptr, SANb);

    // ---- cross attention (residual = ORIGINAL x); CQ+CKV fused ----
    gemm_cross<<<dim3(32, 24), blk, 0, stream>>>(
        SANb, WtCWQ, cbq, CQ, cxb, WtCKV, biasC, CKb, VTc);
    attn_mfma<<<dim3(8, 16, 4), blk, 0, stream>>>(CQ, 1024, CKb, 1024, VTc, cmf, T);
    gemm_bt<0, 1><<<dim3(32, 8, 2), blk, 0, stream>>>(
        T, WtCWO, nullptr, P, 4096, 1024, 1024, 1024, 1, 0, VBIG, nullptr);
    add_ln_kernel<<<4096, blk, 0, stream>>>(P, 2, cbo, x, g, bb, HH, HHb);

    // ---- FFN ----
    gemm_bt<1, 0><<<dim3(32, 32), blk, 0, stream>>>(
        HHb, WtW1, b1, MID, 4096, 4096, 1024, 4096, 0, 0, VBIG, nullptr);
    gemm_bt<0, 1><<<dim3(32, 8, 2), blk, 0, stream>>>(
        MID, WtW2, nullptr, P, 4096, 1024, 4096, 1024, 1, 0, VBIG, nullptr);
    add_ln_kernel<<<4096, blk, 0, stream>>>(P, 2, b2, HH, g, bb, out, nullptr);
}